// Round 11
// baseline (759.270 us; speedup 1.0000x reference)
//
#include <hip/hip_runtime.h>
#include <hip/hip_bf16.h>
#include <cstddef>

#define BB 16
#define LL 2048
#define DM 128
#define DI 256
#define DS 16
#define MP (BB*LL)          // 32768 positions
#define NSEG 64
#define SEGLEN (LL/NSEG)    // 32
#define YSTR 264            // ybuf LDS row stride (shorts)
#define XSTR 40             // sx LDS row stride (floats) for scan2

typedef __attribute__((ext_vector_type(8))) short bf16x8;
typedef __attribute__((ext_vector_type(4))) short bf16x4s;
typedef __attribute__((ext_vector_type(8))) unsigned int ux8;
typedef __attribute__((ext_vector_type(4))) float f32x4;
typedef __hip_bfloat16 bf16;
typedef unsigned int uint;

__device__ inline void bf16split(float x, bf16& h, bf16& l) {
  h = __float2bfloat16(x);
  l = __float2bfloat16(x - __bfloat162float(h));
}
__device__ inline float bf2f(bf16 v) { return __bfloat162float(v); }
__device__ inline void split_bits2(float x, short& hs, short& ls) {
  bf16 hb = __float2bfloat16(x);
  bf16 lb = __float2bfloat16(x - __bfloat162float(hb));
  hs = *(short*)&hb;
  ls = *(short*)&lb;
}
__device__ inline short bfbits(float x) {
  bf16 b = __float2bfloat16(x);
  return *(short*)&b;
}
__device__ inline float sigm(float x) {
  return __builtin_amdgcn_rcpf(1.f + __expf(-x));
}
__device__ inline uint pk2(short h, short l) {
  return (uint)(unsigned short)h | ((uint)(unsigned short)l << 16);
}
__device__ inline uint pack_hl(float x) {
  short hs, ls; split_bits2(x, hs, ls);
  return pk2(hs, ls);
}
__device__ inline float unpack_hl(uint w) {
  return __uint_as_float(w << 16) + __uint_as_float(w & 0xffff0000u);
}

// ---------------------------------------------------------------------------
// Scan helpers (shared)
// ---------------------------------------------------------------------------
__device__ inline float softplus_f(float a) {
  float r = __logf(1.f + __expf(a));
  return a > 15.f ? a : r;
}

__device__ inline void make_powers(float r, float* rp) {
  rp[0] = r;
#pragma unroll
  for (int n = 1; n < 16; n++) {
    int a = (n + 1) >> 1, b = (n + 1) - a;
    rp[n] = rp[a - 1] * rp[b - 1];
  }
}

__device__ inline bool a_is_integer(const float* A_log, int d) {
  bool ok = true;
#pragma unroll
  for (int n = 0; n < DS; n++) {
    float Ad = -__expf(A_log[d * DS + n]);
    ok = ok && (fabsf(Ad + (float)(n + 1)) < 1e-3f);
  }
  return ok;
}

// ---------------------------------------------------------------------------
// Phase D body (fused kernel): scan1 with u from LDS buf (packed uint at
// buf[t*260+d], same bits as u_pk) and x from LDS sxp (24 cols: dt 0..7 +
// B 8..23 — scan1 never reads the C cols). Verbatim scan1 arithmetic.
// ---------------------------------------------------------------------------
template<bool FAST>
__device__ inline void scan1_lds2(int s, int b, int d,
    const float* sxp, const uint* buf,
    const float* __restrict__ dtw, const float* __restrict__ dtb,
    const float* __restrict__ A_log,
    float* __restrict__ sega, float* __restrict__ segh) {
  float wdt[8];
#pragma unroll
  for (int j = 0; j < 8; j++) wdt[j] = dtw[d * 8 + j];
  float bdt = dtb[d];
  float h[DS];
#pragma unroll
  for (int n = 0; n < DS; n++) h[n] = 0.f;
  float R = 1.f;
  float ap[DS];
  if (!FAST) {
#pragma unroll
    for (int n = 0; n < DS; n++) ap[n] = 1.f;
  }
#pragma unroll 4
  for (int t = 0; t < SEGLEN; t++) {
    const float* xr = sxp + t * 24;
    float dt = bdt;
#pragma unroll
    for (int j = 0; j < 8; j++) dt += xr[j] * wdt[j];
    float dl = softplus_f(dt);
    float u = unpack_hl(buf[t * 260 + d]);
    float du = dl * u;
    if (FAST) {
      float rp[DS];
      make_powers(__expf(-dl), rp);
      R *= rp[0];
#pragma unroll
      for (int n = 0; n < DS; n++) h[n] = fmaf(rp[n], h[n], du * xr[8 + n]);
    } else {
#pragma unroll
      for (int n = 0; n < DS; n++) {
        float dA = __expf(dl * (-__expf(A_log[d * DS + n])));
        h[n] = fmaf(dA, h[n], du * xr[8 + n]);
        ap[n] *= dA;
      }
    }
  }
  if (FAST) make_powers(R, ap);
  size_t o = ((size_t)s * 4096 + b * 256 + d) * DS;
#pragma unroll
  for (int j = 0; j < 4; j++) {
    *(float4*)(sega + o + 4 * j) = make_float4(ap[4*j], ap[4*j+1], ap[4*j+2], ap[4*j+3]);
    *(float4*)(segh + o + 4 * j) = make_float4(h[4*j], h[4*j+1], h[4*j+2], h[4*j+3]);
  }
}

// ---------------------------------------------------------------------------
// R11 (fused): phase A split into TWO sequential column-half passes to halve
// the live register set. R9+R10 showed the occupancy limiter is the unified
// VGPR+AGPR footprint (~180/wave: 80 acc AGPR + ~100 VGPR) -> 2 waves/SIMD
// regardless of LDS. Each pass now holds accx[3][2]+accz[2][2] = 40 acc regs
// + 32 B-frag + 24 A-frag (A re-read per pass = L1/L2 hit, HBM unchanged)
// ~= 116 regs <= the (256,4) cap of 128 -> 4 blocks/CU (LDS 36.9 KB also
// permits 4). Per-accumulator MFMA chain (kk order, hh/hl/lh) and epilogue
// expressions untouched => bitwise-identical. Phases B/C/D = R10 verbatim.
// ---------------------------------------------------------------------------
__global__ __launch_bounds__(256, 4) void gemm_inproj_conv(
    const bf16* __restrict__ Ah, const bf16* __restrict__ Al,
    const bf16* __restrict__ Wh, const bf16* __restrict__ Wl,   // in_proj [512][128]
    const bf16* __restrict__ Xh, const bf16* __restrict__ Xl,   // x_proj padded [64][256]
    const float* __restrict__ cw, const float* __restrict__ cb,
    const float* __restrict__ dtw, const float* __restrict__ dtb,
    const float* __restrict__ A_log,
    uint* __restrict__ zs_pk, uint* __restrict__ u_pk,
    float* __restrict__ C,
    float* __restrict__ sega, float* __restrict__ segh) {
  __shared__ uint buf[35 * 260];         // 36,400 B: xm rows -> u rows (in-place) + sx tail
  int tid = threadIdx.x;
  int wave = tid >> 6, lane = tid & 63;
  int r16 = lane & 15, quad = lane >> 4;
  int m0 = blockIdx.x * 32;

  // ---- phase A: in_proj GEMM in two column-half passes (register relief).
  size_t arow[3];
#pragma unroll
  for (int rt = 0; rt < 3; rt++) {
    int rg = m0 - 16 + rt * 16 + r16;
    if (rg < 0) rg = 0;                  // garbage rows are conv-masked
    arow[rt] = (size_t)rg * DM + quad * 8;
  }
#pragma unroll 1
  for (int p = 0; p < 2; p++) {
    size_t browx[2], browz[2];
#pragma unroll
    for (int c2 = 0; c2 < 2; c2++) {
      int ct = p * 2 + c2;
      browx[c2] = (size_t)(wave * 64 + ct * 16 + r16) * DM + quad * 8;
      browz[c2] = (size_t)(256 + wave * 64 + ct * 16 + r16) * DM + quad * 8;
    }
    f32x4 accx[3][2] = {};
    f32x4 accz[2][2] = {};
#pragma unroll
    for (int kk = 0; kk < 4; kk++) {
      int ko = kk * 32;
      bf16x8 ah[3], al[3], bxh[2], bxl[2], bzh[2], bzl[2];
#pragma unroll
      for (int rt = 0; rt < 3; rt++) {
        ah[rt] = *(const bf16x8*)(Ah + arow[rt] + ko);
        al[rt] = *(const bf16x8*)(Al + arow[rt] + ko);
      }
#pragma unroll
      for (int c2 = 0; c2 < 2; c2++) {
        bxh[c2] = *(const bf16x8*)(Wh + browx[c2] + ko);
        bxl[c2] = *(const bf16x8*)(Wl + browx[c2] + ko);
        bzh[c2] = *(const bf16x8*)(Wh + browz[c2] + ko);
        bzl[c2] = *(const bf16x8*)(Wl + browz[c2] + ko);
      }
#pragma unroll
      for (int rt = 0; rt < 3; rt++)
#pragma unroll
        for (int c2 = 0; c2 < 2; c2++) {
          accx[rt][c2] = __builtin_amdgcn_mfma_f32_16x16x32_bf16(ah[rt], bxh[c2], accx[rt][c2], 0, 0, 0);
          accx[rt][c2] = __builtin_amdgcn_mfma_f32_16x16x32_bf16(ah[rt], bxl[c2], accx[rt][c2], 0, 0, 0);
          accx[rt][c2] = __builtin_amdgcn_mfma_f32_16x16x32_bf16(al[rt], bxh[c2], accx[rt][c2], 0, 0, 0);
        }
#pragma unroll
      for (int rz = 0; rz < 2; rz++)
#pragma unroll
        for (int c2 = 0; c2 < 2; c2++) {
          accz[rz][c2] = __builtin_amdgcn_mfma_f32_16x16x32_bf16(ah[rz + 1], bzh[c2], accz[rz][c2], 0, 0, 0);
          accz[rz][c2] = __builtin_amdgcn_mfma_f32_16x16x32_bf16(ah[rz + 1], bzl[c2], accz[rz][c2], 0, 0, 0);
          accz[rz][c2] = __builtin_amdgcn_mfma_f32_16x16x32_bf16(al[rz + 1], bzh[c2], accz[rz][c2], 0, 0, 0);
        }
    }
    // zs epilogue for this column half (identical expression)
#pragma unroll
    for (int rz = 0; rz < 2; rz++)
#pragma unroll
      for (int c2 = 0; c2 < 2; c2++)
#pragma unroll
        for (int r = 0; r < 4; r++) {
          int ct = p * 2 + c2;
          int row = m0 + rz * 16 + quad * 4 + r;
          int col = wave * 64 + ct * 16 + r16;
          float v = accz[rz][c2][r];
          v *= sigm(v);
          zs_pk[(size_t)row * DI + col] = pack_hl(v);
        }
    // xm -> LDS packed for this column half (rows m0-3..m0+31 => lidx 0..34)
#pragma unroll
    for (int rt = 0; rt < 3; rt++)
#pragma unroll
      for (int c2 = 0; c2 < 2; c2++)
#pragma unroll
        for (int r = 0; r < 4; r++) {
          int ct = p * 2 + c2;
          int lidx = rt * 16 + quad * 4 + r - 13;
          if (lidx >= 0)
            buf[lidx * 260 + wave * 64 + ct * 16 + r16] = pack_hl(accx[rt][c2][r]);
        }
  }
  __syncthreads();

  // ---- phase B: conv + SiLU. Thread d: channel d over 32 rows. Writes the
  // packed u IN-PLACE into buf[t][d] (cell read by the same thread at step
  // t-3, or pre-loop for t<3 => per-thread read-before-write, race-free).
  {
    int d = tid;
    float4 w4 = *(const float4*)(cw + d * 4);
    float w0 = w4.x, w1 = w4.y, w2 = w4.z, w3 = w4.w;
    float bias = cb[d];
    float xa = unpack_hl(buf[0 * 260 + d]);
    float xb = unpack_hl(buf[1 * 260 + d]);
    float xc = unpack_hl(buf[2 * 260 + d]);
    int lbase = m0 & (LL - 1);
#pragma unroll 4
    for (int t = 0; t < 32; t++) {
      float xd = unpack_hl(buf[(t + 3) * 260 + d]);
      int l = lbase + t;
      float x0 = xa * ((l >= 3) ? 1.f : 0.f);
      float x1 = xb * ((l >= 2) ? 1.f : 0.f);
      float x2 = xc * ((l >= 1) ? 1.f : 0.f);
      float c0 = bias + w0 * x0 + w1 * x1 + w2 * x2 + w3 * xd;
      float u = c0 * sigm(c0);
      short hs, ls; split_bits2(u, hs, ls);
      uint up = pk2(hs, ls);
      u_pk[(size_t)(m0 + t) * DI + d] = up;
      buf[t * 260 + d] = up;
      xa = xb; xb = xc; xc = xd;
    }
  }
  __syncthreads();   // u rows 0..31 complete in buf; rows 32..34 dead -> sx

  // ---- phase C: x_proj GEMM. 6 tiles over 4 waves; A-frags unpacked from
  // LDS u (same bits as old ubh/ubl). Results -> global C; cols 0..23 also
  // -> LDS sxp (rows 32..34 region, stride 24) for phase D.
  float* sxp = (float*)(buf + 32 * 260);   // 768 floats <= 780 free
  {
    int rt0 = (wave == 3) ? 1 : 0;
    int ct0 = (wave == 0) ? 0 : (wave == 1) ? 1 : (wave == 2) ? 2 : 0;
#pragma unroll 1
    for (int tt = 0; tt < 2; tt++) {
      int rt, ct;
      if (tt == 0) { rt = rt0; ct = ct0; }
      else { if (wave >= 2) break; rt = 1; ct = wave + 1; }
      f32x4 a2 = {};
#pragma unroll
      for (int kk = 0; kk < 8; kk++) {
        int k0 = quad * 8 + kk * 32;
        const uint* ub = buf + (rt * 16 + r16) * 260 + k0;
        bf16x8 ahh, alo;
#pragma unroll
        for (int e = 0; e < 8; e++) {
          uint w = ub[e];
          ahh[e] = (short)(w & 0xffffu);
          alo[e] = (short)(w >> 16);
        }
        size_t br = (size_t)(ct * 16 + r16) * DI + quad * 8 + kk * 32;
        bf16x8 bhh = *(const bf16x8*)(Xh + br);
        bf16x8 blo = *(const bf16x8*)(Xl + br);
        a2 = __builtin_amdgcn_mfma_f32_16x16x32_bf16(ahh, bhh, a2, 0, 0, 0);
        a2 = __builtin_amdgcn_mfma_f32_16x16x32_bf16(ahh, blo, a2, 0, 0, 0);
        a2 = __builtin_amdgcn_mfma_f32_16x16x32_bf16(alo, bhh, a2, 0, 0, 0);
      }
#pragma unroll
      for (int r = 0; r < 4; r++) {
        int row = rt * 16 + quad * 4 + r;
        int col = ct * 16 + r16;
        C[(size_t)(m0 + row) * 64 + col] = a2[r];
        if (col < 24) sxp[row * 24 + col] = a2[r];
      }
    }
  }
  __syncthreads();

  // ---- phase D: scan_phase1; u + x both from LDS. Thread d = channel d.
  {
    int b = blockIdx.x >> 6, s = blockIdx.x & 63, d = tid;
    if (a_is_integer(A_log, d))
      scan1_lds2<true>(s, b, d, sxp, buf, dtw, dtb, A_log, sega, segh);
    else
      scan1_lds2<false>(s, b, d, sxp, buf, dtw, dtb, A_log, sega, segh);
  }
}

// ---------------------------------------------------------------------------
// Encoder (K=12, direct)
// ---------------------------------------------------------------------------
__global__ __launch_bounds__(256) void encoder_kernel(const float* __restrict__ x,
    const float* __restrict__ ew, const float* __restrict__ eb,
    float* __restrict__ h) {
  int idx = blockIdx.x * 256 + threadIdx.x;
  int d = idx & 127, m = idx >> 7;
  float acc = eb[d];
#pragma unroll
  for (int c = 0; c < 12; c++) acc += x[m * 12 + c] * ew[d * 12 + c];
  h[idx] = acc;
}

// ---------------------------------------------------------------------------
// Weight splits
// ---------------------------------------------------------------------------
__global__ void split_w(const float* __restrict__ src, bf16* __restrict__ hi,
                        bf16* __restrict__ lo, int n) {
  int i = blockIdx.x * 256 + threadIdx.x;
  if (i < n) bf16split(src[i], hi[i], lo[i]);
}

__global__ void split_w_pad(const float* __restrict__ src, bf16* __restrict__ hi,
                            bf16* __restrict__ lo) {
  int i = blockIdx.x * 256 + threadIdx.x;   // < 4*64*256
  int l = i >> 14, rem = i & 16383, r = rem >> 8, k = rem & 255;
  float v = (r < 40) ? src[l * 10240 + r * 256 + k] : 0.f;
  bf16split(v, hi[i], lo[i]);
}

// ---------------------------------------------------------------------------
// RMSNorm (layer-0 input only)
// ---------------------------------------------------------------------------
__global__ __launch_bounds__(256) void rmsnorm_kernel(const float* __restrict__ x,
    const float* __restrict__ w, bf16* __restrict__ oh, bf16* __restrict__ ol) {
  int lane = threadIdx.x & 63;
  int pos = blockIdx.x * 4 + (threadIdx.x >> 6);
  const float* row = x + (size_t)pos * DM;
  float v0 = row[lane], v1 = row[lane + 64];
  float ss = v0 * v0 + v1 * v1;
#pragma unroll
  for (int off = 1; off < 64; off <<= 1) ss += __shfl_xor(ss, off);
  float sc = rsqrtf(ss * (1.f / DM) + 1e-5f);
  float a = v0 * sc * w[lane], b = v1 * sc * w[lane + 64];
  size_t o = (size_t)pos * DM;
  bf16split(a, oh[o + lane], ol[o + lane]);
  bf16split(b, oh[o + lane + 64], ol[o + lane + 64]);
}

// load 32 rows x 40 cols of xdbl (cols 0..39) into LDS, stride XSTR
__device__ inline void load_sx(float* sx, const float* xdbl, size_t rbase, int tid) {
#pragma unroll
  for (int j = 0; j < 2; j++) {
    int idx = j * 256 + tid;       // < 320 = 32 rows x 10 float4
    if (idx < 320) {
      int row = idx / 10, c = idx % 10;
      *(float4*)(sx + row * XSTR + c * 4) = *(const float4*)(xdbl + rbase + row * 64 + c * 4);
    }
  }
}

// ---------------------------------------------------------------------------
// R8: scan_combine, 65536 scalar chains over 256 blocks (every CU active).
// ---------------------------------------------------------------------------
__global__ __launch_bounds__(256) void scan_combine(float* __restrict__ sega,
    const float* __restrict__ segh) {
  int g = blockIdx.x * 256 + threadIdx.x;   // chain id = (b*256+d)*16+n
  float h0 = 0.f;
  for (int s = 0; s < NSEG; s++) {
    size_t q = (size_t)s * 65536 + g;
    float a = sega[q];
    float hh = segh[q];
    sega[q] = h0;
    h0 = a * h0 + hh;
  }
}

// ---------------------------------------------------------------------------
// scan2: FUSED scan_phase2 + out_proj + residual + RMSNorm (R6/R8 form).
// ---------------------------------------------------------------------------
template<bool FAST>
__device__ inline void scan2_to_lds(int s, int b, int d, const float* sx,
    const uint* __restrict__ u_pk, const uint* __restrict__ zs_pk,
    const float* __restrict__ dtw, const float* __restrict__ dtb,
    const float* __restrict__ A_log, const float* __restrict__ Dp,
    const float* __restrict__ sega, short* __restrict__ ybuf) {
  float wdt[8];
#pragma unroll
  for (int j = 0; j < 8; j++) wdt[j] = dtw[d * 8 + j];
  float bdt = dtb[d];
  float h[DS];
  size_t o = ((size_t)s * 4096 + b * 256 + d) * DS;
#pragma unroll
  for (int n = 0; n < DS; n++) h[n] = sega[o + n];
  float Dd = Dp[d];
  size_t base = (size_t)b * LL + (size_t)s * SEGLEN;
  const uint* up = u_pk + base * DI + d;
  const uint* zp = zs_pk + base * DI + d;
  uint ub = *up, zb = *zp;
#pragma unroll 4
  for (int t = 0; t < SEGLEN; t++) {
    up += DI; zp += DI;
    uint ub_next = *up;
    uint zb_next = *zp;
    const float* xr = sx + t * XSTR;
    float dt = bdt;
#pragma unroll
    for (int j = 0; j < 8; j++) dt += xr[j] * wdt[j];
    float dl = softplus_f(dt);
    float u = unpack_hl(ub);
    float du = dl * u;
    float acc = 0.f;
    if (FAST) {
      float rp[DS];
      make_powers(__expf(-dl), rp);
#pragma unroll
      for (int n = 0; n < DS; n++) {
        h[n] = fmaf(rp[n], h[n], du * xr[8 + n]);
        acc = fmaf(h[n], xr[24 + n], acc);
      }
    } else {
#pragma unroll
      for (int n = 0; n < DS; n++) {
        float dA = __expf(dl * (-__expf(A_log[d * DS + n])));
        h[n] = fmaf(dA, h[n], du * xr[8 + n]);
        acc = fmaf(h[n], xr[24 + n], acc);
      }
    }
    float zs = unpack_hl(zb);
    float yv = (acc + u * Dd) * zs;
    ybuf[t * YSTR + d] = bfbits(yv);
    ub = ub_next; zb = zb_next;
  }
}

__global__ __launch_bounds__(256, 6) void scan2_outproj(
    const uint* __restrict__ u_pk, const uint* __restrict__ zs_pk,
    const float* __restrict__ xdbl, const float* __restrict__ dtw,
    const float* __restrict__ dtb, const float* __restrict__ A_log,
    const float* __restrict__ Dp, const float* __restrict__ sega,
    const bf16* __restrict__ Wh, const bf16* __restrict__ Wl,
    float* __restrict__ hbuf, const float* __restrict__ nw,
    float* __restrict__ of, bf16* __restrict__ oh, bf16* __restrict__ ol) {
  __shared__ float sx[SEGLEN * XSTR];      // 5 KB
  __shared__ short ybuf[32 * YSTR];        // 16.9 KB (bf16 y; later fp32 tile)
  int s = blockIdx.x, b = blockIdx.y;
  int tid = threadIdx.x, d = tid;
  size_t rbase = ((size_t)b * LL + (size_t)s * SEGLEN) * 64;
  load_sx(sx, xdbl, rbase, tid);
  __syncthreads();
  if (a_is_integer(A_log, d))
    scan2_to_lds<true>(s, b, d, sx, u_pk, zs_pk, dtw, dtb, A_log, Dp, sega, ybuf);
  else
    scan2_to_lds<false>(s, b, d, sx, u_pk, zs_pk, dtw, dtb, A_log, Dp, sega, ybuf);
  __syncthreads();
  // out_proj: C[32x128] = y[32x256] @ Wop[128x256]^T, wave covers 32 cols
  int wave = tid >> 6, lane = tid & 63;
  int r16 = lane & 15, quad = lane >> 4;
  int n0 = wave * 32;
  size_t brow[2];
#pragma unroll
  for (int j = 0; j < 2; j++)
    brow[j] = (size_t)(n0 + j * 16 + r16) * DI + quad * 8;
  f32x4 acc[2][2] = {};
#pragma unroll
  for (int kk = 0; kk < 8; kk++) {
    int k0 = quad * 8 + kk * 32;
    bf16x8 ah[2], bh[2], bl[2];
#pragma unroll
    for (int i = 0; i < 2; i++)
      ah[i] = *(const bf16x8*)(ybuf + (i * 16 + r16) * YSTR + k0);
#pragma unroll
    for (int j = 0; j < 2; j++) {
      bh[j] = *(const bf16x8*)(Wh + brow[j] + kk * 32);
      bl[j] = *(const bf16x8*)(Wl + brow[j] + kk * 32);
    }
#pragma unroll
    for (int i = 0; i < 2; i++)
#pragma unroll
      for (int j = 0; j < 2; j++) {
        acc[i][j] = __builtin_amdgcn_mfma_f32_16x16x32_bf16(ah[i], bh[j], acc[i][j], 0, 0, 0);
        acc[i][j] = __builtin_amdgcn_mfma_f32_16x16x32_bf16(ah[i], bl[j], acc[i][j], 0, 0, 0);
      }
  }
  __syncthreads();   // all LDS y reads done; reuse ybuf as fp32 tile 32x132
  float* tile = (float*)ybuf;
#pragma unroll
  for (int i = 0; i < 2; i++)
#pragma unroll
    for (int j = 0; j < 2; j++)
#pragma unroll
      for (int r = 0; r < 4; r++) {
        int rl = i * 16 + quad * 4 + r;
        int col = n0 + j * 16 + r16;
        tile[rl * 132 + col] = acc[i][j][r];
      }
  __syncthreads();
  // epilogue: residual + rmsnorm + bf16 split, coalesced
  size_t mbase = (size_t)b * LL + (size_t)s * SEGLEN;
#pragma unroll
  for (int it = 0; it < 4; it++) {
    int idx = it * 256 + tid;
    int row = idx >> 5, c4 = idx & 31;
    size_t g = (mbase + row) * DM + c4 * 4;
    float4 hv = *(float4*)(hbuf + g);
    const float* tp = tile + row * 132 + c4 * 4;
    float4 v = make_float4(tp[0] + hv.x, tp[1] + hv.y, tp[2] + hv.z, tp[3] + hv.w);
    *(float4*)(hbuf + g) = v;
    float ss = v.x * v.x + v.y * v.y + v.z * v.z + v.w * v.w;
    ss += __shfl_xor(ss, 1);
    ss += __shfl_xor(ss, 2);
    ss += __shfl_xor(ss, 4);
    ss += __shfl_xor(ss, 8);
    ss += __shfl_xor(ss, 16);
    float sc = rsqrtf(ss * (1.f / DM) + 1e-5f);
    float4 w4 = *(const float4*)(nw + c4 * 4);
    float n0v = v.x * sc * w4.x, n1v = v.y * sc * w4.y;
    float n2v = v.z * sc * w4.z, n3v = v.w * sc * w4.w;
    if (of) *(float4*)(of + g) = make_float4(n0v, n1v, n2v, n3v);
    short h0s, l0s, h1s, l1s, h2s, l2s, h3s, l3s;
    split_bits2(n0v, h0s, l0s); split_bits2(n1v, h1s, l1s);
    split_bits2(n2v, h2s, l2s); split_bits2(n3v, h3s, l3s);
    bf16x4s hb, lb;
    hb[0] = h0s; hb[1] = h1s; hb[2] = h2s; hb[3] = h3s;
    lb[0] = l0s; lb[1] = l1s; lb[2] = l2s; lb[3] = l3s;
    *(bf16x4s*)(oh + g) = hb;
    *(bf16x4s*)(ol + g) = lb;
  }
}

// ---------------------------------------------------------------------------
// Pooling (deterministic) + classifier
// ---------------------------------------------------------------------------
__global__ __launch_bounds__(256) void pool_partial(const float* __restrict__ fn,
    float* __restrict__ partial) {
  __shared__ float red[256];
  int b = blockIdx.x, c = blockIdx.y;
  int tid = threadIdx.x;
  int d = tid & 127, rp_ = tid >> 7;
  float s = 0.f;
  size_t base = (size_t)b * LL + c * 256;
  for (int i = 0; i < 128; i++) {
    int row = i * 2 + rp_;
    s += fn[(base + row) * DM + d];
  }
  red[tid] = s;
  __syncthreads();
  if (tid < 128) partial[((size_t)b * 8 + c) * 128 + tid] = red[tid] + red[tid + 128];
}

__global__ void pool_reduce(const float* __restrict__ partial,
    float* __restrict__ pooled) {
  int idx = blockIdx.x * 256 + threadIdx.x;   // 2048
  int b = idx >> 7, d = idx & 127;
  float s = 0.f;
#pragma unroll
  for (int c = 0; c < 8; c++) s += partial[((size_t)b * 8 + c) * 128 + d];
  pooled[idx] = s * (1.f / LL);
}

__global__ void cls_kernel(const float* __restrict__ pooled,
    const float* __restrict__ cw, const float* __restrict__ cb,
    float* __restrict__ out) {
  int t = threadIdx.x;
  if (t < 80) {
    int b = t / 5, c = t % 5;
    float acc = cb[c];
    for (int d = 0; d < DM; d++) acc += pooled[b * DM + d] * cw[c * DM + d];
    out[t] = acc;
  }
}

// ---------------------------------------------------------------------------
extern "C" void kernel_launch(void* const* d_in, const int* in_sizes, int n_in,
                              void* d_out, int out_size, void* d_ws, size_t ws_size,
                              hipStream_t stream) {
  const float* x         = (const float*)d_in[0];
  const float* enc_w     = (const float*)d_in[1];
  const float* enc_b     = (const float*)d_in[2];
  const float* norm_w    = (const float*)d_in[3];
  const float* in_proj_w = (const float*)d_in[4];
  const float* conv_w    = (const float*)d_in[5];
  const float* conv_b    = (const float*)d_in[6];
  const float* x_proj_w  = (const float*)d_in[7];
  const float* dt_proj_w = (const float*)d_in[8];
  const float* dt_proj_b = (const float*)d_in[9];
  const float* A_log     = (const float*)d_in[10];
  const float* Dp        = (const float*)d_in[11];
  const float* out_proj_w= (const float*)d_in[12];
  const float* norm_f_w  = (const float*)d_in[13];
  const float* cls_w     = (const float*)d_in[14];
  const float* cls_b     = (const float*)d_in[15];
  float* out = (float*)d_out;

  float* ws = (float*)d_ws;
  float* h       = ws;                       // 4,194,304
  float* xdbl    = ws + 4194304;             // 2,097,152
  float* sega    = ws + 6291456;             // 4,194,304
  float* segh    = ws + 10485760;            // 4,194,304
  uint*  zs_pk   = (uint*)(ws + 14680064);   // 8,388,608
  uint*  u_pk    = (uint*)(ws + 23068672);   // 8,388,608
  uint*  xm_pk   = (uint*)(ws + 31457280);   // fnorm alias
  float* partial = ws + 39845888;            // 16,384
  float* pooled  = ws + 39862272;            // 2,048
  bf16* u0     = (bf16*)(ws + 39864320);
  bf16* xn_hi  = u0;                         // MP*128
  bf16* xn_lo  = u0 + 4194304;
  bf16* wip_hi = u0 + 8388608;               // 262,144
  bf16* wip_lo = wip_hi + 262144;
  bf16* wxp_hi = wip_lo + 262144;            // 65,536 (padded)
  bf16* wxp_lo = wxp_hi + 65536;
  bf16* wop_hi = wxp_lo + 65536;             // 131,072
  bf16* wop_lo = wop_hi + 131072;
  float* fnorm = (float*)xm_pk;

  split_w<<<1024, 256, 0, stream>>>(in_proj_w, wip_hi, wip_lo, 262144);
  split_w_pad<<<256, 256, 0, stream>>>(x_proj_w, wxp_hi, wxp_lo);
  split_w<<<512, 256, 0, stream>>>(out_proj_w, wop_hi, wop_lo, 131072);

  encoder_kernel<<<MP * DM / 256, 256, 0, stream>>>(x, enc_w, enc_b, h);
  rmsnorm_kernel<<<MP / 4, 256, 0, stream>>>(h, norm_w, xn_hi, xn_lo);

  for (int i = 0; i < 4; i++) {
    gemm_inproj_conv<<<MP / 32, 256, 0, stream>>>(xn_hi, xn_lo,
        wip_hi + i * 65536, wip_lo + i * 65536,
        wxp_hi + i * 16384, wxp_lo + i * 16384,
        conv_w + i * DI * 4, conv_b + i * DI,
        dt_proj_w + i * 2048, dt_proj_b + i * DI, A_log + i * DI * DS,
        zs_pk, u_pk, xdbl, sega, segh);
    scan_combine<<<256, 256, 0, stream>>>(sega, segh);
    scan2_outproj<<<dim3(NSEG, BB), 256, 0, stream>>>(u_pk, zs_pk, xdbl,
        dt_proj_w + i * 2048, dt_proj_b + i * DI, A_log + i * DI * DS,
        Dp + i * DI, sega, wop_hi + i * 32768, wop_lo + i * 32768, h,
        (i < 3) ? norm_w + (i + 1) * DM : norm_f_w,
        (i < 3) ? nullptr : fnorm, xn_hi, xn_lo);
  }

  pool_partial<<<dim3(BB, 8), 256, 0, stream>>>(fnorm, partial);
  pool_reduce<<<8, 256, 0, stream>>>(partial, pooled);
  cls_kernel<<<1, 128, 0, stream>>>(pooled, cls_w, cls_b, out);
}

// Round 12
// 697.947 us; speedup vs baseline: 1.0879x; 1.0879x over previous
//
#include <hip/hip_runtime.h>
#include <hip/hip_bf16.h>
#include <cstddef>

#define BB 16
#define LL 2048
#define DM 128
#define DI 256
#define DS 16
#define MP (BB*LL)          // 32768 positions
#define NSEG 64
#define SEGLEN (LL/NSEG)    // 32
#define YSTR 264            // ybuf LDS row stride (shorts)
#define XSTR 40             // sx LDS row stride (floats) for scan2

typedef __attribute__((ext_vector_type(8))) short bf16x8;
typedef __attribute__((ext_vector_type(4))) short bf16x4s;
typedef __attribute__((ext_vector_type(8))) unsigned int ux8;
typedef __attribute__((ext_vector_type(4))) float f32x4;
typedef __hip_bfloat16 bf16;
typedef unsigned int uint;

__device__ inline void bf16split(float x, bf16& h, bf16& l) {
  h = __float2bfloat16(x);
  l = __float2bfloat16(x - __bfloat162float(h));
}
__device__ inline float bf2f(bf16 v) { return __bfloat162float(v); }
__device__ inline void split_bits2(float x, short& hs, short& ls) {
  bf16 hb = __float2bfloat16(x);
  bf16 lb = __float2bfloat16(x - __bfloat162float(hb));
  hs = *(short*)&hb;
  ls = *(short*)&lb;
}
__device__ inline short bfbits(float x) {
  bf16 b = __float2bfloat16(x);
  return *(short*)&b;
}
__device__ inline float sigm(float x) {
  return __builtin_amdgcn_rcpf(1.f + __expf(-x));
}
__device__ inline uint pk2(short h, short l) {
  return (uint)(unsigned short)h | ((uint)(unsigned short)l << 16);
}
__device__ inline uint pack_hl(float x) {
  short hs, ls; split_bits2(x, hs, ls);
  return pk2(hs, ls);
}
__device__ inline float unpack_hl(uint w) {
  return __uint_as_float(w << 16) + __uint_as_float(w & 0xffff0000u);
}

// ---------------------------------------------------------------------------
// Scan helpers (shared)
// ---------------------------------------------------------------------------
__device__ inline float softplus_f(float a) {
  float r = __logf(1.f + __expf(a));
  return a > 15.f ? a : r;
}

__device__ inline void make_powers(float r, float* rp) {
  rp[0] = r;
#pragma unroll
  for (int n = 1; n < 16; n++) {
    int a = (n + 1) >> 1, b = (n + 1) - a;
    rp[n] = rp[a - 1] * rp[b - 1];
  }
}

__device__ inline bool a_is_integer(const float* A_log, int d) {
  bool ok = true;
#pragma unroll
  for (int n = 0; n < DS; n++) {
    float Ad = -__expf(A_log[d * DS + n]);
    ok = ok && (fabsf(Ad + (float)(n + 1)) < 1e-3f);
  }
  return ok;
}

// ---------------------------------------------------------------------------
// Phase D body (fused kernel): scan1 with u from LDS buf (packed uint at
// buf[t*260+d], same bits as u_pk) and x from LDS sxp (24 cols: dt 0..7 +
// B 8..23 — scan1 never reads the C cols). Verbatim scan1 arithmetic.
// ---------------------------------------------------------------------------
template<bool FAST>
__device__ inline void scan1_lds2(int s, int b, int d,
    const float* sxp, const uint* buf,
    const float* __restrict__ dtw, const float* __restrict__ dtb,
    const float* __restrict__ A_log,
    float* __restrict__ sega, float* __restrict__ segh) {
  float wdt[8];
#pragma unroll
  for (int j = 0; j < 8; j++) wdt[j] = dtw[d * 8 + j];
  float bdt = dtb[d];
  float h[DS];
#pragma unroll
  for (int n = 0; n < DS; n++) h[n] = 0.f;
  float R = 1.f;
  float ap[DS];
  if (!FAST) {
#pragma unroll
    for (int n = 0; n < DS; n++) ap[n] = 1.f;
  }
#pragma unroll 4
  for (int t = 0; t < SEGLEN; t++) {
    const float* xr = sxp + t * 24;
    float dt = bdt;
#pragma unroll
    for (int j = 0; j < 8; j++) dt += xr[j] * wdt[j];
    float dl = softplus_f(dt);
    float u = unpack_hl(buf[t * 260 + d]);
    float du = dl * u;
    if (FAST) {
      float rp[DS];
      make_powers(__expf(-dl), rp);
      R *= rp[0];
#pragma unroll
      for (int n = 0; n < DS; n++) h[n] = fmaf(rp[n], h[n], du * xr[8 + n]);
    } else {
#pragma unroll
      for (int n = 0; n < DS; n++) {
        float dA = __expf(dl * (-__expf(A_log[d * DS + n])));
        h[n] = fmaf(dA, h[n], du * xr[8 + n]);
        ap[n] *= dA;
      }
    }
  }
  if (FAST) make_powers(R, ap);
  size_t o = ((size_t)s * 4096 + b * 256 + d) * DS;
#pragma unroll
  for (int j = 0; j < 4; j++) {
    *(float4*)(sega + o + 4 * j) = make_float4(ap[4*j], ap[4*j+1], ap[4*j+2], ap[4*j+3]);
    *(float4*)(segh + o + 4 * j) = make_float4(h[4*j], h[4*j+1], h[4*j+2], h[4*j+3]);
  }
}

// ---------------------------------------------------------------------------
// R12 (fused): R11's split phase A + __launch_bounds__(256,3) (~168-reg cap).
// R11 confirmed service-rate ~ occupancy (1.34 TB/s @2 blk -> 2.54 @~4 blk)
// but the (256,4)=128-reg cap spilled (+163 MB scratch, VGPR 64). The 168
// cap comfortably holds the split-A live set (~116+overhead) -> 3 blocks/CU
// with NO spill. Everything else byte-identical to R11/R10.
// ---------------------------------------------------------------------------
__global__ __launch_bounds__(256, 3) void gemm_inproj_conv(
    const bf16* __restrict__ Ah, const bf16* __restrict__ Al,
    const bf16* __restrict__ Wh, const bf16* __restrict__ Wl,   // in_proj [512][128]
    const bf16* __restrict__ Xh, const bf16* __restrict__ Xl,   // x_proj padded [64][256]
    const float* __restrict__ cw, const float* __restrict__ cb,
    const float* __restrict__ dtw, const float* __restrict__ dtb,
    const float* __restrict__ A_log,
    uint* __restrict__ zs_pk, uint* __restrict__ u_pk,
    float* __restrict__ C,
    float* __restrict__ sega, float* __restrict__ segh) {
  __shared__ uint buf[35 * 260];         // 36,400 B: xm rows -> u rows (in-place) + sx tail
  int tid = threadIdx.x;
  int wave = tid >> 6, lane = tid & 63;
  int r16 = lane & 15, quad = lane >> 4;
  int m0 = blockIdx.x * 32;

  // ---- phase A: in_proj GEMM in two column-half passes (register relief).
  size_t arow[3];
#pragma unroll
  for (int rt = 0; rt < 3; rt++) {
    int rg = m0 - 16 + rt * 16 + r16;
    if (rg < 0) rg = 0;                  // garbage rows are conv-masked
    arow[rt] = (size_t)rg * DM + quad * 8;
  }
#pragma unroll 1
  for (int p = 0; p < 2; p++) {
    size_t browx[2], browz[2];
#pragma unroll
    for (int c2 = 0; c2 < 2; c2++) {
      int ct = p * 2 + c2;
      browx[c2] = (size_t)(wave * 64 + ct * 16 + r16) * DM + quad * 8;
      browz[c2] = (size_t)(256 + wave * 64 + ct * 16 + r16) * DM + quad * 8;
    }
    f32x4 accx[3][2] = {};
    f32x4 accz[2][2] = {};
#pragma unroll
    for (int kk = 0; kk < 4; kk++) {
      int ko = kk * 32;
      bf16x8 ah[3], al[3], bxh[2], bxl[2], bzh[2], bzl[2];
#pragma unroll
      for (int rt = 0; rt < 3; rt++) {
        ah[rt] = *(const bf16x8*)(Ah + arow[rt] + ko);
        al[rt] = *(const bf16x8*)(Al + arow[rt] + ko);
      }
#pragma unroll
      for (int c2 = 0; c2 < 2; c2++) {
        bxh[c2] = *(const bf16x8*)(Wh + browx[c2] + ko);
        bxl[c2] = *(const bf16x8*)(Wl + browx[c2] + ko);
        bzh[c2] = *(const bf16x8*)(Wh + browz[c2] + ko);
        bzl[c2] = *(const bf16x8*)(Wl + browz[c2] + ko);
      }
#pragma unroll
      for (int rt = 0; rt < 3; rt++)
#pragma unroll
        for (int c2 = 0; c2 < 2; c2++) {
          accx[rt][c2] = __builtin_amdgcn_mfma_f32_16x16x32_bf16(ah[rt], bxh[c2], accx[rt][c2], 0, 0, 0);
          accx[rt][c2] = __builtin_amdgcn_mfma_f32_16x16x32_bf16(ah[rt], bxl[c2], accx[rt][c2], 0, 0, 0);
          accx[rt][c2] = __builtin_amdgcn_mfma_f32_16x16x32_bf16(al[rt], bxh[c2], accx[rt][c2], 0, 0, 0);
        }
#pragma unroll
      for (int rz = 0; rz < 2; rz++)
#pragma unroll
        for (int c2 = 0; c2 < 2; c2++) {
          accz[rz][c2] = __builtin_amdgcn_mfma_f32_16x16x32_bf16(ah[rz + 1], bzh[c2], accz[rz][c2], 0, 0, 0);
          accz[rz][c2] = __builtin_amdgcn_mfma_f32_16x16x32_bf16(ah[rz + 1], bzl[c2], accz[rz][c2], 0, 0, 0);
          accz[rz][c2] = __builtin_amdgcn_mfma_f32_16x16x32_bf16(al[rz + 1], bzh[c2], accz[rz][c2], 0, 0, 0);
        }
    }
    // zs epilogue for this column half (identical expression)
#pragma unroll
    for (int rz = 0; rz < 2; rz++)
#pragma unroll
      for (int c2 = 0; c2 < 2; c2++)
#pragma unroll
        for (int r = 0; r < 4; r++) {
          int ct = p * 2 + c2;
          int row = m0 + rz * 16 + quad * 4 + r;
          int col = wave * 64 + ct * 16 + r16;
          float v = accz[rz][c2][r];
          v *= sigm(v);
          zs_pk[(size_t)row * DI + col] = pack_hl(v);
        }
    // xm -> LDS packed for this column half (rows m0-3..m0+31 => lidx 0..34)
#pragma unroll
    for (int rt = 0; rt < 3; rt++)
#pragma unroll
      for (int c2 = 0; c2 < 2; c2++)
#pragma unroll
        for (int r = 0; r < 4; r++) {
          int ct = p * 2 + c2;
          int lidx = rt * 16 + quad * 4 + r - 13;
          if (lidx >= 0)
            buf[lidx * 260 + wave * 64 + ct * 16 + r16] = pack_hl(accx[rt][c2][r]);
        }
  }
  __syncthreads();

  // ---- phase B: conv + SiLU. Thread d: channel d over 32 rows. Writes the
  // packed u IN-PLACE into buf[t][d] (cell read by the same thread at step
  // t-3, or pre-loop for t<3 => per-thread read-before-write, race-free).
  {
    int d = tid;
    float4 w4 = *(const float4*)(cw + d * 4);
    float w0 = w4.x, w1 = w4.y, w2 = w4.z, w3 = w4.w;
    float bias = cb[d];
    float xa = unpack_hl(buf[0 * 260 + d]);
    float xb = unpack_hl(buf[1 * 260 + d]);
    float xc = unpack_hl(buf[2 * 260 + d]);
    int lbase = m0 & (LL - 1);
#pragma unroll 4
    for (int t = 0; t < 32; t++) {
      float xd = unpack_hl(buf[(t + 3) * 260 + d]);
      int l = lbase + t;
      float x0 = xa * ((l >= 3) ? 1.f : 0.f);
      float x1 = xb * ((l >= 2) ? 1.f : 0.f);
      float x2 = xc * ((l >= 1) ? 1.f : 0.f);
      float c0 = bias + w0 * x0 + w1 * x1 + w2 * x2 + w3 * xd;
      float u = c0 * sigm(c0);
      short hs, ls; split_bits2(u, hs, ls);
      uint up = pk2(hs, ls);
      u_pk[(size_t)(m0 + t) * DI + d] = up;
      buf[t * 260 + d] = up;
      xa = xb; xb = xc; xc = xd;
    }
  }
  __syncthreads();   // u rows 0..31 complete in buf; rows 32..34 dead -> sx

  // ---- phase C: x_proj GEMM. 6 tiles over 4 waves; A-frags unpacked from
  // LDS u (same bits as old ubh/ubl). Results -> global C; cols 0..23 also
  // -> LDS sxp (rows 32..34 region, stride 24) for phase D.
  float* sxp = (float*)(buf + 32 * 260);   // 768 floats <= 780 free
  {
    int rt0 = (wave == 3) ? 1 : 0;
    int ct0 = (wave == 0) ? 0 : (wave == 1) ? 1 : (wave == 2) ? 2 : 0;
#pragma unroll 1
    for (int tt = 0; tt < 2; tt++) {
      int rt, ct;
      if (tt == 0) { rt = rt0; ct = ct0; }
      else { if (wave >= 2) break; rt = 1; ct = wave + 1; }
      f32x4 a2 = {};
#pragma unroll
      for (int kk = 0; kk < 8; kk++) {
        int k0 = quad * 8 + kk * 32;
        const uint* ub = buf + (rt * 16 + r16) * 260 + k0;
        bf16x8 ahh, alo;
#pragma unroll
        for (int e = 0; e < 8; e++) {
          uint w = ub[e];
          ahh[e] = (short)(w & 0xffffu);
          alo[e] = (short)(w >> 16);
        }
        size_t br = (size_t)(ct * 16 + r16) * DI + quad * 8 + kk * 32;
        bf16x8 bhh = *(const bf16x8*)(Xh + br);
        bf16x8 blo = *(const bf16x8*)(Xl + br);
        a2 = __builtin_amdgcn_mfma_f32_16x16x32_bf16(ahh, bhh, a2, 0, 0, 0);
        a2 = __builtin_amdgcn_mfma_f32_16x16x32_bf16(ahh, blo, a2, 0, 0, 0);
        a2 = __builtin_amdgcn_mfma_f32_16x16x32_bf16(alo, bhh, a2, 0, 0, 0);
      }
#pragma unroll
      for (int r = 0; r < 4; r++) {
        int row = rt * 16 + quad * 4 + r;
        int col = ct * 16 + r16;
        C[(size_t)(m0 + row) * 64 + col] = a2[r];
        if (col < 24) sxp[row * 24 + col] = a2[r];
      }
    }
  }
  __syncthreads();

  // ---- phase D: scan_phase1; u + x both from LDS. Thread d = channel d.
  {
    int b = blockIdx.x >> 6, s = blockIdx.x & 63, d = tid;
    if (a_is_integer(A_log, d))
      scan1_lds2<true>(s, b, d, sxp, buf, dtw, dtb, A_log, sega, segh);
    else
      scan1_lds2<false>(s, b, d, sxp, buf, dtw, dtb, A_log, sega, segh);
  }
}

// ---------------------------------------------------------------------------
// Encoder (K=12, direct)
// ---------------------------------------------------------------------------
__global__ __launch_bounds__(256) void encoder_kernel(const float* __restrict__ x,
    const float* __restrict__ ew, const float* __restrict__ eb,
    float* __restrict__ h) {
  int idx = blockIdx.x * 256 + threadIdx.x;
  int d = idx & 127, m = idx >> 7;
  float acc = eb[d];
#pragma unroll
  for (int c = 0; c < 12; c++) acc += x[m * 12 + c] * ew[d * 12 + c];
  h[idx] = acc;
}

// ---------------------------------------------------------------------------
// Weight splits
// ---------------------------------------------------------------------------
__global__ void split_w(const float* __restrict__ src, bf16* __restrict__ hi,
                        bf16* __restrict__ lo, int n) {
  int i = blockIdx.x * 256 + threadIdx.x;
  if (i < n) bf16split(src[i], hi[i], lo[i]);
}

__global__ void split_w_pad(const float* __restrict__ src, bf16* __restrict__ hi,
                            bf16* __restrict__ lo) {
  int i = blockIdx.x * 256 + threadIdx.x;   // < 4*64*256
  int l = i >> 14, rem = i & 16383, r = rem >> 8, k = rem & 255;
  float v = (r < 40) ? src[l * 10240 + r * 256 + k] : 0.f;
  bf16split(v, hi[i], lo[i]);
}

// ---------------------------------------------------------------------------
// RMSNorm (layer-0 input only)
// ---------------------------------------------------------------------------
__global__ __launch_bounds__(256) void rmsnorm_kernel(const float* __restrict__ x,
    const float* __restrict__ w, bf16* __restrict__ oh, bf16* __restrict__ ol) {
  int lane = threadIdx.x & 63;
  int pos = blockIdx.x * 4 + (threadIdx.x >> 6);
  const float* row = x + (size_t)pos * DM;
  float v0 = row[lane], v1 = row[lane + 64];
  float ss = v0 * v0 + v1 * v1;
#pragma unroll
  for (int off = 1; off < 64; off <<= 1) ss += __shfl_xor(ss, off);
  float sc = rsqrtf(ss * (1.f / DM) + 1e-5f);
  float a = v0 * sc * w[lane], b = v1 * sc * w[lane + 64];
  size_t o = (size_t)pos * DM;
  bf16split(a, oh[o + lane], ol[o + lane]);
  bf16split(b, oh[o + lane + 64], ol[o + lane + 64]);
}

// load 32 rows x 40 cols of xdbl (cols 0..39) into LDS, stride XSTR
__device__ inline void load_sx(float* sx, const float* xdbl, size_t rbase, int tid) {
#pragma unroll
  for (int j = 0; j < 2; j++) {
    int idx = j * 256 + tid;       // < 320 = 32 rows x 10 float4
    if (idx < 320) {
      int row = idx / 10, c = idx % 10;
      *(float4*)(sx + row * XSTR + c * 4) = *(const float4*)(xdbl + rbase + row * 64 + c * 4);
    }
  }
}

// ---------------------------------------------------------------------------
// R8: scan_combine, 65536 scalar chains over 256 blocks (every CU active).
// ---------------------------------------------------------------------------
__global__ __launch_bounds__(256) void scan_combine(float* __restrict__ sega,
    const float* __restrict__ segh) {
  int g = blockIdx.x * 256 + threadIdx.x;   // chain id = (b*256+d)*16+n
  float h0 = 0.f;
  for (int s = 0; s < NSEG; s++) {
    size_t q = (size_t)s * 65536 + g;
    float a = sega[q];
    float hh = segh[q];
    sega[q] = h0;
    h0 = a * h0 + hh;
  }
}

// ---------------------------------------------------------------------------
// scan2: FUSED scan_phase2 + out_proj + residual + RMSNorm (R6/R8 form).
// ---------------------------------------------------------------------------
template<bool FAST>
__device__ inline void scan2_to_lds(int s, int b, int d, const float* sx,
    const uint* __restrict__ u_pk, const uint* __restrict__ zs_pk,
    const float* __restrict__ dtw, const float* __restrict__ dtb,
    const float* __restrict__ A_log, const float* __restrict__ Dp,
    const float* __restrict__ sega, short* __restrict__ ybuf) {
  float wdt[8];
#pragma unroll
  for (int j = 0; j < 8; j++) wdt[j] = dtw[d * 8 + j];
  float bdt = dtb[d];
  float h[DS];
  size_t o = ((size_t)s * 4096 + b * 256 + d) * DS;
#pragma unroll
  for (int n = 0; n < DS; n++) h[n] = sega[o + n];
  float Dd = Dp[d];
  size_t base = (size_t)b * LL + (size_t)s * SEGLEN;
  const uint* up = u_pk + base * DI + d;
  const uint* zp = zs_pk + base * DI + d;
  uint ub = *up, zb = *zp;
#pragma unroll 4
  for (int t = 0; t < SEGLEN; t++) {
    up += DI; zp += DI;
    uint ub_next = *up;
    uint zb_next = *zp;
    const float* xr = sx + t * XSTR;
    float dt = bdt;
#pragma unroll
    for (int j = 0; j < 8; j++) dt += xr[j] * wdt[j];
    float dl = softplus_f(dt);
    float u = unpack_hl(ub);
    float du = dl * u;
    float acc = 0.f;
    if (FAST) {
      float rp[DS];
      make_powers(__expf(-dl), rp);
#pragma unroll
      for (int n = 0; n < DS; n++) {
        h[n] = fmaf(rp[n], h[n], du * xr[8 + n]);
        acc = fmaf(h[n], xr[24 + n], acc);
      }
    } else {
#pragma unroll
      for (int n = 0; n < DS; n++) {
        float dA = __expf(dl * (-__expf(A_log[d * DS + n])));
        h[n] = fmaf(dA, h[n], du * xr[8 + n]);
        acc = fmaf(h[n], xr[24 + n], acc);
      }
    }
    float zs = unpack_hl(zb);
    float yv = (acc + u * Dd) * zs;
    ybuf[t * YSTR + d] = bfbits(yv);
    ub = ub_next; zb = zb_next;
  }
}

__global__ __launch_bounds__(256, 6) void scan2_outproj(
    const uint* __restrict__ u_pk, const uint* __restrict__ zs_pk,
    const float* __restrict__ xdbl, const float* __restrict__ dtw,
    const float* __restrict__ dtb, const float* __restrict__ A_log,
    const float* __restrict__ Dp, const float* __restrict__ sega,
    const bf16* __restrict__ Wh, const bf16* __restrict__ Wl,
    float* __restrict__ hbuf, const float* __restrict__ nw,
    float* __restrict__ of, bf16* __restrict__ oh, bf16* __restrict__ ol) {
  __shared__ float sx[SEGLEN * XSTR];      // 5 KB
  __shared__ short ybuf[32 * YSTR];        // 16.9 KB (bf16 y; later fp32 tile)
  int s = blockIdx.x, b = blockIdx.y;
  int tid = threadIdx.x, d = tid;
  size_t rbase = ((size_t)b * LL + (size_t)s * SEGLEN) * 64;
  load_sx(sx, xdbl, rbase, tid);
  __syncthreads();
  if (a_is_integer(A_log, d))
    scan2_to_lds<true>(s, b, d, sx, u_pk, zs_pk, dtw, dtb, A_log, Dp, sega, ybuf);
  else
    scan2_to_lds<false>(s, b, d, sx, u_pk, zs_pk, dtw, dtb, A_log, Dp, sega, ybuf);
  __syncthreads();
  // out_proj: C[32x128] = y[32x256] @ Wop[128x256]^T, wave covers 32 cols
  int wave = tid >> 6, lane = tid & 63;
  int r16 = lane & 15, quad = lane >> 4;
  int n0 = wave * 32;
  size_t brow[2];
#pragma unroll
  for (int j = 0; j < 2; j++)
    brow[j] = (size_t)(n0 + j * 16 + r16) * DI + quad * 8;
  f32x4 acc[2][2] = {};
#pragma unroll
  for (int kk = 0; kk < 8; kk++) {
    int k0 = quad * 8 + kk * 32;
    bf16x8 ah[2], bh[2], bl[2];
#pragma unroll
    for (int i = 0; i < 2; i++)
      ah[i] = *(const bf16x8*)(ybuf + (i * 16 + r16) * YSTR + k0);
#pragma unroll
    for (int j = 0; j < 2; j++) {
      bh[j] = *(const bf16x8*)(Wh + brow[j] + kk * 32);
      bl[j] = *(const bf16x8*)(Wl + brow[j] + kk * 32);
    }
#pragma unroll
    for (int i = 0; i < 2; i++)
#pragma unroll
      for (int j = 0; j < 2; j++) {
        acc[i][j] = __builtin_amdgcn_mfma_f32_16x16x32_bf16(ah[i], bh[j], acc[i][j], 0, 0, 0);
        acc[i][j] = __builtin_amdgcn_mfma_f32_16x16x32_bf16(ah[i], bl[j], acc[i][j], 0, 0, 0);
      }
  }
  __syncthreads();   // all LDS y reads done; reuse ybuf as fp32 tile 32x132
  float* tile = (float*)ybuf;
#pragma unroll
  for (int i = 0; i < 2; i++)
#pragma unroll
    for (int j = 0; j < 2; j++)
#pragma unroll
      for (int r = 0; r < 4; r++) {
        int rl = i * 16 + quad * 4 + r;
        int col = n0 + j * 16 + r16;
        tile[rl * 132 + col] = acc[i][j][r];
      }
  __syncthreads();
  // epilogue: residual + rmsnorm + bf16 split, coalesced
  size_t mbase = (size_t)b * LL + (size_t)s * SEGLEN;
#pragma unroll
  for (int it = 0; it < 4; it++) {
    int idx = it * 256 + tid;
    int row = idx >> 5, c4 = idx & 31;
    size_t g = (mbase + row) * DM + c4 * 4;
    float4 hv = *(float4*)(hbuf + g);
    const float* tp = tile + row * 132 + c4 * 4;
    float4 v = make_float4(tp[0] + hv.x, tp[1] + hv.y, tp[2] + hv.z, tp[3] + hv.w);
    *(float4*)(hbuf + g) = v;
    float ss = v.x * v.x + v.y * v.y + v.z * v.z + v.w * v.w;
    ss += __shfl_xor(ss, 1);
    ss += __shfl_xor(ss, 2);
    ss += __shfl_xor(ss, 4);
    ss += __shfl_xor(ss, 8);
    ss += __shfl_xor(ss, 16);
    float sc = rsqrtf(ss * (1.f / DM) + 1e-5f);
    float4 w4 = *(const float4*)(nw + c4 * 4);
    float n0v = v.x * sc * w4.x, n1v = v.y * sc * w4.y;
    float n2v = v.z * sc * w4.z, n3v = v.w * sc * w4.w;
    if (of) *(float4*)(of + g) = make_float4(n0v, n1v, n2v, n3v);
    short h0s, l0s, h1s, l1s, h2s, l2s, h3s, l3s;
    split_bits2(n0v, h0s, l0s); split_bits2(n1v, h1s, l1s);
    split_bits2(n2v, h2s, l2s); split_bits2(n3v, h3s, l3s);
    bf16x4s hb, lb;
    hb[0] = h0s; hb[1] = h1s; hb[2] = h2s; hb[3] = h3s;
    lb[0] = l0s; lb[1] = l1s; lb[2] = l2s; lb[3] = l3s;
    *(bf16x4s*)(oh + g) = hb;
    *(bf16x4s*)(ol + g) = lb;
  }
}

// ---------------------------------------------------------------------------
// Pooling (deterministic) + classifier
// ---------------------------------------------------------------------------
__global__ __launch_bounds__(256) void pool_partial(const float* __restrict__ fn,
    float* __restrict__ partial) {
  __shared__ float red[256];
  int b = blockIdx.x, c = blockIdx.y;
  int tid = threadIdx.x;
  int d = tid & 127, rp_ = tid >> 7;
  float s = 0.f;
  size_t base = (size_t)b * LL + c * 256;
  for (int i = 0; i < 128; i++) {
    int row = i * 2 + rp_;
    s += fn[(base + row) * DM + d];
  }
  red[tid] = s;
  __syncthreads();
  if (tid < 128) partial[((size_t)b * 8 + c) * 128 + tid] = red[tid] + red[tid + 128];
}

__global__ void pool_reduce(const float* __restrict__ partial,
    float* __restrict__ pooled) {
  int idx = blockIdx.x * 256 + threadIdx.x;   // 2048
  int b = idx >> 7, d = idx & 127;
  float s = 0.f;
#pragma unroll
  for (int c = 0; c < 8; c++) s += partial[((size_t)b * 8 + c) * 128 + d];
  pooled[idx] = s * (1.f / LL);
}

__global__ void cls_kernel(const float* __restrict__ pooled,
    const float* __restrict__ cw, const float* __restrict__ cb,
    float* __restrict__ out) {
  int t = threadIdx.x;
  if (t < 80) {
    int b = t / 5, c = t % 5;
    float acc = cb[c];
    for (int d = 0; d < DM; d++) acc += pooled[b * DM + d] * cw[c * DM + d];
    out[t] = acc;
  }
}

// ---------------------------------------------------------------------------
extern "C" void kernel_launch(void* const* d_in, const int* in_sizes, int n_in,
                              void* d_out, int out_size, void* d_ws, size_t ws_size,
                              hipStream_t stream) {
  const float* x         = (const float*)d_in[0];
  const float* enc_w     = (const float*)d_in[1];
  const float* enc_b     = (const float*)d_in[2];
  const float* norm_w    = (const float*)d_in[3];
  const float* in_proj_w = (const float*)d_in[4];
  const float* conv_w    = (const float*)d_in[5];
  const float* conv_b    = (const float*)d_in[6];
  const float* x_proj_w  = (const float*)d_in[7];
  const float* dt_proj_w = (const float*)d_in[8];
  const float* dt_proj_b = (const float*)d_in[9];
  const float* A_log     = (const float*)d_in[10];
  const float* Dp        = (const float*)d_in[11];
  const float* out_proj_w= (const float*)d_in[12];
  const float* norm_f_w  = (const float*)d_in[13];
  const float* cls_w     = (const float*)d_in[14];
  const float* cls_b     = (const float*)d_in[15];
  float* out = (float*)d_out;

  float* ws = (float*)d_ws;
  float* h       = ws;                       // 4,194,304
  float* xdbl    = ws + 4194304;             // 2,097,152
  float* sega    = ws + 6291456;             // 4,194,304
  float* segh    = ws + 10485760;            // 4,194,304
  uint*  zs_pk   = (uint*)(ws + 14680064);   // 8,388,608
  uint*  u_pk    = (uint*)(ws + 23068672);   // 8,388,608
  uint*  xm_pk   = (uint*)(ws + 31457280);   // fnorm alias
  float* partial = ws + 39845888;            // 16,384
  float* pooled  = ws + 39862272;            // 2,048
  bf16* u0     = (bf16*)(ws + 39864320);
  bf16* xn_hi  = u0;                         // MP*128
  bf16* xn_lo  = u0 + 4194304;
  bf16* wip_hi = u0 + 8388608;               // 262,144
  bf16* wip_lo = wip_hi + 262144;
  bf16* wxp_hi = wip_lo + 262144;            // 65,536 (padded)
  bf16* wxp_lo = wxp_hi + 65536;
  bf16* wop_hi = wxp_lo + 65536;             // 131,072
  bf16* wop_lo = wop_hi + 131072;
  float* fnorm = (float*)xm_pk;

  split_w<<<1024, 256, 0, stream>>>(in_proj_w, wip_hi, wip_lo, 262144);
  split_w_pad<<<256, 256, 0, stream>>>(x_proj_w, wxp_hi, wxp_lo);
  split_w<<<512, 256, 0, stream>>>(out_proj_w, wop_hi, wop_lo, 131072);

  encoder_kernel<<<MP * DM / 256, 256, 0, stream>>>(x, enc_w, enc_b, h);
  rmsnorm_kernel<<<MP / 4, 256, 0, stream>>>(h, norm_w, xn_hi, xn_lo);

  for (int i = 0; i < 4; i++) {
    gemm_inproj_conv<<<MP / 32, 256, 0, stream>>>(xn_hi, xn_lo,
        wip_hi + i * 65536, wip_lo + i * 65536,
        wxp_hi + i * 16384, wxp_lo + i * 16384,
        conv_w + i * DI * 4, conv_b + i * DI,
        dt_proj_w + i * 2048, dt_proj_b + i * DI, A_log + i * DI * DS,
        zs_pk, u_pk, xdbl, sega, segh);
    scan_combine<<<256, 256, 0, stream>>>(sega, segh);
    scan2_outproj<<<dim3(NSEG, BB), 256, 0, stream>>>(u_pk, zs_pk, xdbl,
        dt_proj_w + i * 2048, dt_proj_b + i * DI, A_log + i * DI * DS,
        Dp + i * DI, sega, wop_hi + i * 32768, wop_lo + i * 32768, h,
        (i < 3) ? norm_w + (i + 1) * DM : norm_f_w,
        (i < 3) ? nullptr : fnorm, xn_hi, xn_lo);
  }

  pool_partial<<<dim3(BB, 8), 256, 0, stream>>>(fnorm, partial);
  pool_reduce<<<8, 256, 0, stream>>>(partial, pooled);
  cls_kernel<<<1, 128, 0, stream>>>(pooled, cls_w, cls_b, out);
}

// Round 13
// 632.280 us; speedup vs baseline: 1.2008x; 1.1039x over previous
//
#include <hip/hip_runtime.h>
#include <hip/hip_bf16.h>
#include <cstddef>

#define BB 16
#define LL 2048
#define DM 128
#define DI 256
#define DS 16
#define MP (BB*LL)          // 32768 positions
#define NSEG 64
#define SEGLEN (LL/NSEG)    // 32
#define YSTR 264            // ybuf LDS row stride (shorts)
#define XSTR 40             // sx LDS row stride (floats) for scan2
#define SXS 48              // in-kernel sx stride (floats) for fused phase D

typedef __attribute__((ext_vector_type(8))) short bf16x8;
typedef __attribute__((ext_vector_type(4))) short bf16x4s;
typedef __attribute__((ext_vector_type(8))) unsigned int ux8;
typedef __attribute__((ext_vector_type(4))) float f32x4;
typedef __hip_bfloat16 bf16;
typedef unsigned int uint;

__device__ inline void bf16split(float x, bf16& h, bf16& l) {
  h = __float2bfloat16(x);
  l = __float2bfloat16(x - __bfloat162float(h));
}
__device__ inline float bf2f(bf16 v) { return __bfloat162float(v); }
__device__ inline void split_bits2(float x, short& hs, short& ls) {
  bf16 hb = __float2bfloat16(x);
  bf16 lb = __float2bfloat16(x - __bfloat162float(hb));
  hs = *(short*)&hb;
  ls = *(short*)&lb;
}
__device__ inline short bfbits(float x) {
  bf16 b = __float2bfloat16(x);
  return *(short*)&b;
}
__device__ inline float sigm(float x) {
  return __builtin_amdgcn_rcpf(1.f + __expf(-x));
}
__device__ inline uint pk2(short h, short l) {
  return (uint)(unsigned short)h | ((uint)(unsigned short)l << 16);
}
__device__ inline uint pack_hl(float x) {
  short hs, ls; split_bits2(x, hs, ls);
  return pk2(hs, ls);
}
__device__ inline float unpack_hl(uint w) {
  return __uint_as_float(w << 16) + __uint_as_float(w & 0xffff0000u);
}

// ---------------------------------------------------------------------------
// Scan helpers (shared)
// ---------------------------------------------------------------------------
__device__ inline float softplus_f(float a) {
  float r = __logf(1.f + __expf(a));
  return a > 15.f ? a : r;
}

__device__ inline void make_powers(float r, float* rp) {
  rp[0] = r;
#pragma unroll
  for (int n = 1; n < 16; n++) {
    int a = (n + 1) >> 1, b = (n + 1) - a;
    rp[n] = rp[a - 1] * rp[b - 1];
  }
}

__device__ inline bool a_is_integer(const float* A_log, int d) {
  bool ok = true;
#pragma unroll
  for (int n = 0; n < DS; n++) {
    float Ad = -__expf(A_log[d * DS + n]);
    ok = ok && (fabsf(Ad + (float)(n + 1)) < 1e-3f);
  }
  return ok;
}

// ---------------------------------------------------------------------------
// Phase D body (fused kernel): scan1 with u from LDS buf (packed uint at
// buf[t*260+d], same bits as u_pk) and x from LDS sxp (24 cols: dt 0..7 +
// B 8..23 — scan1 never reads the C cols). Verbatim scan1 arithmetic.
// ---------------------------------------------------------------------------
template<bool FAST>
__device__ inline void scan1_lds2(int s, int b, int d,
    const float* sxp, const uint* buf,
    const float* __restrict__ dtw, const float* __restrict__ dtb,
    const float* __restrict__ A_log,
    float* __restrict__ sega, float* __restrict__ segh) {
  float wdt[8];
#pragma unroll
  for (int j = 0; j < 8; j++) wdt[j] = dtw[d * 8 + j];
  float bdt = dtb[d];
  float h[DS];
#pragma unroll
  for (int n = 0; n < DS; n++) h[n] = 0.f;
  float R = 1.f;
  float ap[DS];
  if (!FAST) {
#pragma unroll
    for (int n = 0; n < DS; n++) ap[n] = 1.f;
  }
#pragma unroll 4
  for (int t = 0; t < SEGLEN; t++) {
    const float* xr = sxp + t * 24;
    float dt = bdt;
#pragma unroll
    for (int j = 0; j < 8; j++) dt += xr[j] * wdt[j];
    float dl = softplus_f(dt);
    float u = unpack_hl(buf[t * 260 + d]);
    float du = dl * u;
    if (FAST) {
      float rp[DS];
      make_powers(__expf(-dl), rp);
      R *= rp[0];
#pragma unroll
      for (int n = 0; n < DS; n++) h[n] = fmaf(rp[n], h[n], du * xr[8 + n]);
    } else {
#pragma unroll
      for (int n = 0; n < DS; n++) {
        float dA = __expf(dl * (-__expf(A_log[d * DS + n])));
        h[n] = fmaf(dA, h[n], du * xr[8 + n]);
        ap[n] *= dA;
      }
    }
  }
  if (FAST) make_powers(R, ap);
  size_t o = ((size_t)s * 4096 + b * 256 + d) * DS;
#pragma unroll
  for (int j = 0; j < 4; j++) {
    *(float4*)(sega + o + 4 * j) = make_float4(ap[4*j], ap[4*j+1], ap[4*j+2], ap[4*j+3]);
    *(float4*)(segh + o + 4 * j) = make_float4(h[4*j], h[4*j+1], h[4*j+2], h[4*j+3]);
  }
}

// ---------------------------------------------------------------------------
// R13 (fused): exact R10 form (634us champion). R9/R11/R12 proved the phase-A
// register footprint (~80 AGPR acc + ~100 VGPR) cannot be capped or split
// without spill / cache-missing re-reads that cancel the occupancy gain —
// lever retired. u aliased in-place into xmb cells; sx in dead rows 32..34.
// ---------------------------------------------------------------------------
__global__ __launch_bounds__(256, 2) void gemm_inproj_conv(
    const bf16* __restrict__ Ah, const bf16* __restrict__ Al,
    const bf16* __restrict__ Wh, const bf16* __restrict__ Wl,   // in_proj [512][128]
    const bf16* __restrict__ Xh, const bf16* __restrict__ Xl,   // x_proj padded [64][256]
    const float* __restrict__ cw, const float* __restrict__ cb,
    const float* __restrict__ dtw, const float* __restrict__ dtb,
    const float* __restrict__ A_log,
    uint* __restrict__ zs_pk, uint* __restrict__ u_pk,
    float* __restrict__ C,
    float* __restrict__ sega, float* __restrict__ segh) {
  __shared__ uint buf[35 * 260];         // 36,400 B: xm rows -> u rows (in-place) + sx tail
  int tid = threadIdx.x;
  int wave = tid >> 6, lane = tid & 63;
  int r16 = lane & 15, quad = lane >> 4;
  int m0 = blockIdx.x * 32;

  // ---- phase A: in_proj GEMM. A rows m0-16..m0+31 (3 row-tiles, clamped).
  size_t arow[3];
#pragma unroll
  for (int rt = 0; rt < 3; rt++) {
    int rg = m0 - 16 + rt * 16 + r16;
    if (rg < 0) rg = 0;                  // garbage rows are conv-masked
    arow[rt] = (size_t)rg * DM + quad * 8;
  }
  size_t browx[4], browz[4];
#pragma unroll
  for (int ct = 0; ct < 4; ct++) {
    browx[ct] = (size_t)(wave * 64 + ct * 16 + r16) * DM + quad * 8;
    browz[ct] = (size_t)(256 + wave * 64 + ct * 16 + r16) * DM + quad * 8;
  }
  f32x4 accx[3][4] = {};
  f32x4 accz[2][4] = {};
#pragma unroll
  for (int kk = 0; kk < 4; kk++) {
    int ko = kk * 32;
    bf16x8 ah[3], al[3], bxh[4], bxl[4], bzh[4], bzl[4];
#pragma unroll
    for (int rt = 0; rt < 3; rt++) {
      ah[rt] = *(const bf16x8*)(Ah + arow[rt] + ko);
      al[rt] = *(const bf16x8*)(Al + arow[rt] + ko);
    }
#pragma unroll
    for (int ct = 0; ct < 4; ct++) {
      bxh[ct] = *(const bf16x8*)(Wh + browx[ct] + ko);
      bxl[ct] = *(const bf16x8*)(Wl + browx[ct] + ko);
      bzh[ct] = *(const bf16x8*)(Wh + browz[ct] + ko);
      bzl[ct] = *(const bf16x8*)(Wl + browz[ct] + ko);
    }
#pragma unroll
    for (int rt = 0; rt < 3; rt++)
#pragma unroll
      for (int ct = 0; ct < 4; ct++) {
        accx[rt][ct] = __builtin_amdgcn_mfma_f32_16x16x32_bf16(ah[rt], bxh[ct], accx[rt][ct], 0, 0, 0);
        accx[rt][ct] = __builtin_amdgcn_mfma_f32_16x16x32_bf16(ah[rt], bxl[ct], accx[rt][ct], 0, 0, 0);
        accx[rt][ct] = __builtin_amdgcn_mfma_f32_16x16x32_bf16(al[rt], bxh[ct], accx[rt][ct], 0, 0, 0);
      }
#pragma unroll
    for (int rz = 0; rz < 2; rz++)
#pragma unroll
      for (int ct = 0; ct < 4; ct++) {
        accz[rz][ct] = __builtin_amdgcn_mfma_f32_16x16x32_bf16(ah[rz + 1], bzh[ct], accz[rz][ct], 0, 0, 0);
        accz[rz][ct] = __builtin_amdgcn_mfma_f32_16x16x32_bf16(ah[rz + 1], bzl[ct], accz[rz][ct], 0, 0, 0);
        accz[rz][ct] = __builtin_amdgcn_mfma_f32_16x16x32_bf16(al[rz + 1], bzh[ct], accz[rz][ct], 0, 0, 0);
      }
  }
  // zs epilogue (identical expression: v *= sigm(v); pack_hl)
#pragma unroll
  for (int rz = 0; rz < 2; rz++)
#pragma unroll
    for (int ct = 0; ct < 4; ct++)
#pragma unroll
      for (int r = 0; r < 4; r++) {
        int row = m0 + rz * 16 + quad * 4 + r;
        int col = wave * 64 + ct * 16 + r16;
        float v = accz[rz][ct][r];
        v *= sigm(v);
        zs_pk[(size_t)row * DI + col] = pack_hl(v);
      }
  // xm -> LDS packed (rows m0-3..m0+31 => lidx 0..34)
#pragma unroll
  for (int rt = 0; rt < 3; rt++)
#pragma unroll
    for (int ct = 0; ct < 4; ct++)
#pragma unroll
      for (int r = 0; r < 4; r++) {
        int lidx = rt * 16 + quad * 4 + r - 13;
        if (lidx >= 0)
          buf[lidx * 260 + wave * 64 + ct * 16 + r16] = pack_hl(accx[rt][ct][r]);
      }
  __syncthreads();

  // ---- phase B: conv + SiLU. Thread d: channel d over 32 rows. Writes the
  // packed u IN-PLACE into buf[t][d] (cell read by the same thread at step
  // t-3, or pre-loop for t<3 => per-thread read-before-write, race-free).
  {
    int d = tid;
    float4 w4 = *(const float4*)(cw + d * 4);
    float w0 = w4.x, w1 = w4.y, w2 = w4.z, w3 = w4.w;
    float bias = cb[d];
    float xa = unpack_hl(buf[0 * 260 + d]);
    float xb = unpack_hl(buf[1 * 260 + d]);
    float xc = unpack_hl(buf[2 * 260 + d]);
    int lbase = m0 & (LL - 1);
#pragma unroll 4
    for (int t = 0; t < 32; t++) {
      float xd = unpack_hl(buf[(t + 3) * 260 + d]);
      int l = lbase + t;
      float x0 = xa * ((l >= 3) ? 1.f : 0.f);
      float x1 = xb * ((l >= 2) ? 1.f : 0.f);
      float x2 = xc * ((l >= 1) ? 1.f : 0.f);
      float c0 = bias + w0 * x0 + w1 * x1 + w2 * x2 + w3 * xd;
      float u = c0 * sigm(c0);
      short hs, ls; split_bits2(u, hs, ls);
      uint up = pk2(hs, ls);
      u_pk[(size_t)(m0 + t) * DI + d] = up;
      buf[t * 260 + d] = up;
      xa = xb; xb = xc; xc = xd;
    }
  }
  __syncthreads();   // u rows 0..31 complete in buf; rows 32..34 dead -> sx

  // ---- phase C: x_proj GEMM. 6 tiles over 4 waves; A-frags unpacked from
  // LDS u (same bits as old ubh/ubl). Results -> global C; cols 0..23 also
  // -> LDS sxp (rows 32..34 region, stride 24) for phase D.
  float* sxp = (float*)(buf + 32 * 260);   // 768 floats <= 780 free
  {
    int rt0 = (wave == 3) ? 1 : 0;
    int ct0 = (wave == 0) ? 0 : (wave == 1) ? 1 : (wave == 2) ? 2 : 0;
#pragma unroll 1
    for (int tt = 0; tt < 2; tt++) {
      int rt, ct;
      if (tt == 0) { rt = rt0; ct = ct0; }
      else { if (wave >= 2) break; rt = 1; ct = wave + 1; }
      f32x4 a2 = {};
#pragma unroll
      for (int kk = 0; kk < 8; kk++) {
        int k0 = quad * 8 + kk * 32;
        const uint* ub = buf + (rt * 16 + r16) * 260 + k0;
        bf16x8 ahh, alo;
#pragma unroll
        for (int e = 0; e < 8; e++) {
          uint w = ub[e];
          ahh[e] = (short)(w & 0xffffu);
          alo[e] = (short)(w >> 16);
        }
        size_t br = (size_t)(ct * 16 + r16) * DI + quad * 8 + kk * 32;
        bf16x8 bhh = *(const bf16x8*)(Xh + br);
        bf16x8 blo = *(const bf16x8*)(Xl + br);
        a2 = __builtin_amdgcn_mfma_f32_16x16x32_bf16(ahh, bhh, a2, 0, 0, 0);
        a2 = __builtin_amdgcn_mfma_f32_16x16x32_bf16(ahh, blo, a2, 0, 0, 0);
        a2 = __builtin_amdgcn_mfma_f32_16x16x32_bf16(alo, bhh, a2, 0, 0, 0);
      }
#pragma unroll
      for (int r = 0; r < 4; r++) {
        int row = rt * 16 + quad * 4 + r;
        int col = ct * 16 + r16;
        C[(size_t)(m0 + row) * 64 + col] = a2[r];
        if (col < 24) sxp[row * 24 + col] = a2[r];
      }
    }
  }
  __syncthreads();

  // ---- phase D: scan_phase1; u + x both from LDS. Thread d = channel d.
  {
    int b = blockIdx.x >> 6, s = blockIdx.x & 63, d = tid;
    if (a_is_integer(A_log, d))
      scan1_lds2<true>(s, b, d, sxp, buf, dtw, dtb, A_log, sega, segh);
    else
      scan1_lds2<false>(s, b, d, sxp, buf, dtw, dtb, A_log, sega, segh);
  }
}

// ---------------------------------------------------------------------------
// R13: FUSED encoder + RMSNorm (layer-0 prologue). rmsnorm used to re-read
// the 16 MB h the encoder just wrote; now the encoder dot (same c-order) is
// computed in-register, h written (still the residual input), and the
// rmsnorm applied immediately (identical expression) => bitwise-identical,
// one less 16 MB read + one less launch.
// ---------------------------------------------------------------------------
__global__ __launch_bounds__(256) void enc_norm_kernel(const float* __restrict__ x,
    const float* __restrict__ ew, const float* __restrict__ eb,
    const float* __restrict__ w, float* __restrict__ h,
    bf16* __restrict__ oh, bf16* __restrict__ ol) {
  int lane = threadIdx.x & 63;
  int pos = blockIdx.x * 4 + (threadIdx.x >> 6);
  const float* xr = x + (size_t)pos * 12;
  float v0 = eb[lane], v1 = eb[lane + 64];
#pragma unroll
  for (int c = 0; c < 12; c++) {
    float xv = xr[c];
    v0 += xv * ew[lane * 12 + c];
    v1 += xv * ew[(lane + 64) * 12 + c];
  }
  size_t o = (size_t)pos * DM;
  h[o + lane] = v0;
  h[o + lane + 64] = v1;
  float ss = v0 * v0 + v1 * v1;
#pragma unroll
  for (int off = 1; off < 64; off <<= 1) ss += __shfl_xor(ss, off);
  float sc = rsqrtf(ss * (1.f / DM) + 1e-5f);
  float a = v0 * sc * w[lane], b = v1 * sc * w[lane + 64];
  bf16split(a, oh[o + lane], ol[o + lane]);
  bf16split(b, oh[o + lane + 64], ol[o + lane + 64]);
}

// ---------------------------------------------------------------------------
// Weight splits
// ---------------------------------------------------------------------------
__global__ void split_w(const float* __restrict__ src, bf16* __restrict__ hi,
                        bf16* __restrict__ lo, int n) {
  int i = blockIdx.x * 256 + threadIdx.x;
  if (i < n) bf16split(src[i], hi[i], lo[i]);
}

__global__ void split_w_pad(const float* __restrict__ src, bf16* __restrict__ hi,
                            bf16* __restrict__ lo) {
  int i = blockIdx.x * 256 + threadIdx.x;   // < 4*64*256
  int l = i >> 14, rem = i & 16383, r = rem >> 8, k = rem & 255;
  float v = (r < 40) ? src[l * 10240 + r * 256 + k] : 0.f;
  bf16split(v, hi[i], lo[i]);
}

// load 32 rows x 40 cols of xdbl (cols 0..39) into LDS, stride XSTR
__device__ inline void load_sx(float* sx, const float* xdbl, size_t rbase, int tid) {
#pragma unroll
  for (int j = 0; j < 2; j++) {
    int idx = j * 256 + tid;       // < 320 = 32 rows x 10 float4
    if (idx < 320) {
      int row = idx / 10, c = idx % 10;
      *(float4*)(sx + row * XSTR + c * 4) = *(const float4*)(xdbl + rbase + row * 64 + c * 4);
    }
  }
}

// ---------------------------------------------------------------------------
// R8: scan_combine, 65536 scalar chains over 256 blocks (every CU active).
// ---------------------------------------------------------------------------
__global__ __launch_bounds__(256) void scan_combine(float* __restrict__ sega,
    const float* __restrict__ segh) {
  int g = blockIdx.x * 256 + threadIdx.x;   // chain id = (b*256+d)*16+n
  float h0 = 0.f;
  for (int s = 0; s < NSEG; s++) {
    size_t q = (size_t)s * 65536 + g;
    float a = sega[q];
    float hh = segh[q];
    sega[q] = h0;
    h0 = a * h0 + hh;
  }
}

// ---------------------------------------------------------------------------
// scan2: FUSED scan_phase2 + out_proj + residual + RMSNorm (R6/R8 form).
// R13: launch_bounds (256,6) -> (256,7): VGPR 40 + 16 acc << 512/7=73 cap,
// LDS 22 KB x 7 = 154 KB <= 160 KB -> one more resident block/CU.
// ---------------------------------------------------------------------------
template<bool FAST>
__device__ inline void scan2_to_lds(int s, int b, int d, const float* sx,
    const uint* __restrict__ u_pk, const uint* __restrict__ zs_pk,
    const float* __restrict__ dtw, const float* __restrict__ dtb,
    const float* __restrict__ A_log, const float* __restrict__ Dp,
    const float* __restrict__ sega, short* __restrict__ ybuf) {
  float wdt[8];
#pragma unroll
  for (int j = 0; j < 8; j++) wdt[j] = dtw[d * 8 + j];
  float bdt = dtb[d];
  float h[DS];
  size_t o = ((size_t)s * 4096 + b * 256 + d) * DS;
#pragma unroll
  for (int n = 0; n < DS; n++) h[n] = sega[o + n];
  float Dd = Dp[d];
  size_t base = (size_t)b * LL + (size_t)s * SEGLEN;
  const uint* up = u_pk + base * DI + d;
  const uint* zp = zs_pk + base * DI + d;
  uint ub = *up, zb = *zp;
#pragma unroll 4
  for (int t = 0; t < SEGLEN; t++) {
    up += DI; zp += DI;
    uint ub_next = *up;
    uint zb_next = *zp;
    const float* xr = sx + t * XSTR;
    float dt = bdt;
#pragma unroll
    for (int j = 0; j < 8; j++) dt += xr[j] * wdt[j];
    float dl = softplus_f(dt);
    float u = unpack_hl(ub);
    float du = dl * u;
    float acc = 0.f;
    if (FAST) {
      float rp[DS];
      make_powers(__expf(-dl), rp);
#pragma unroll
      for (int n = 0; n < DS; n++) {
        h[n] = fmaf(rp[n], h[n], du * xr[8 + n]);
        acc = fmaf(h[n], xr[24 + n], acc);
      }
    } else {
#pragma unroll
      for (int n = 0; n < DS; n++) {
        float dA = __expf(dl * (-__expf(A_log[d * DS + n])));
        h[n] = fmaf(dA, h[n], du * xr[8 + n]);
        acc = fmaf(h[n], xr[24 + n], acc);
      }
    }
    float zs = unpack_hl(zb);
    float yv = (acc + u * Dd) * zs;
    ybuf[t * YSTR + d] = bfbits(yv);
    ub = ub_next; zb = zb_next;
  }
}

__global__ __launch_bounds__(256, 7) void scan2_outproj(
    const uint* __restrict__ u_pk, const uint* __restrict__ zs_pk,
    const float* __restrict__ xdbl, const float* __restrict__ dtw,
    const float* __restrict__ dtb, const float* __restrict__ A_log,
    const float* __restrict__ Dp, const float* __restrict__ sega,
    const bf16* __restrict__ Wh, const bf16* __restrict__ Wl,
    float* __restrict__ hbuf, const float* __restrict__ nw,
    float* __restrict__ of, bf16* __restrict__ oh, bf16* __restrict__ ol) {
  __shared__ float sx[SEGLEN * XSTR];      // 5 KB
  __shared__ short ybuf[32 * YSTR];        // 16.9 KB (bf16 y; later fp32 tile)
  int s = blockIdx.x, b = blockIdx.y;
  int tid = threadIdx.x, d = tid;
  size_t rbase = ((size_t)b * LL + (size_t)s * SEGLEN) * 64;
  load_sx(sx, xdbl, rbase, tid);
  __syncthreads();
  if (a_is_integer(A_log, d))
    scan2_to_lds<true>(s, b, d, sx, u_pk, zs_pk, dtw, dtb, A_log, Dp, sega, ybuf);
  else
    scan2_to_lds<false>(s, b, d, sx, u_pk, zs_pk, dtw, dtb, A_log, Dp, sega, ybuf);
  __syncthreads();
  // out_proj: C[32x128] = y[32x256] @ Wop[128x256]^T, wave covers 32 cols
  int wave = tid >> 6, lane = tid & 63;
  int r16 = lane & 15, quad = lane >> 4;
  int n0 = wave * 32;
  size_t brow[2];
#pragma unroll
  for (int j = 0; j < 2; j++)
    brow[j] = (size_t)(n0 + j * 16 + r16) * DI + quad * 8;
  f32x4 acc[2][2] = {};
#pragma unroll
  for (int kk = 0; kk < 8; kk++) {
    int k0 = quad * 8 + kk * 32;
    bf16x8 ah[2], bh[2], bl[2];
#pragma unroll
    for (int i = 0; i < 2; i++)
      ah[i] = *(const bf16x8*)(ybuf + (i * 16 + r16) * YSTR + k0);
#pragma unroll
    for (int j = 0; j < 2; j++) {
      bh[j] = *(const bf16x8*)(Wh + brow[j] + kk * 32);
      bl[j] = *(const bf16x8*)(Wl + brow[j] + kk * 32);
    }
#pragma unroll
    for (int i = 0; i < 2; i++)
#pragma unroll
      for (int j = 0; j < 2; j++) {
        acc[i][j] = __builtin_amdgcn_mfma_f32_16x16x32_bf16(ah[i], bh[j], acc[i][j], 0, 0, 0);
        acc[i][j] = __builtin_amdgcn_mfma_f32_16x16x32_bf16(ah[i], bl[j], acc[i][j], 0, 0, 0);
      }
  }
  __syncthreads();   // all LDS y reads done; reuse ybuf as fp32 tile 32x132
  float* tile = (float*)ybuf;
#pragma unroll
  for (int i = 0; i < 2; i++)
#pragma unroll
    for (int j = 0; j < 2; j++)
#pragma unroll
      for (int r = 0; r < 4; r++) {
        int rl = i * 16 + quad * 4 + r;
        int col = n0 + j * 16 + r16;
        tile[rl * 132 + col] = acc[i][j][r];
      }
  __syncthreads();
  // epilogue: residual + rmsnorm + bf16 split, coalesced
  size_t mbase = (size_t)b * LL + (size_t)s * SEGLEN;
#pragma unroll
  for (int it = 0; it < 4; it++) {
    int idx = it * 256 + tid;
    int row = idx >> 5, c4 = idx & 31;
    size_t g = (mbase + row) * DM + c4 * 4;
    float4 hv = *(float4*)(hbuf + g);
    const float* tp = tile + row * 132 + c4 * 4;
    float4 v = make_float4(tp[0] + hv.x, tp[1] + hv.y, tp[2] + hv.z, tp[3] + hv.w);
    *(float4*)(hbuf + g) = v;
    float ss = v.x * v.x + v.y * v.y + v.z * v.z + v.w * v.w;
    ss += __shfl_xor(ss, 1);
    ss += __shfl_xor(ss, 2);
    ss += __shfl_xor(ss, 4);
    ss += __shfl_xor(ss, 8);
    ss += __shfl_xor(ss, 16);
    float sc = rsqrtf(ss * (1.f / DM) + 1e-5f);
    float4 w4 = *(const float4*)(nw + c4 * 4);
    float n0v = v.x * sc * w4.x, n1v = v.y * sc * w4.y;
    float n2v = v.z * sc * w4.z, n3v = v.w * sc * w4.w;
    if (of) *(float4*)(of + g) = make_float4(n0v, n1v, n2v, n3v);
    short h0s, l0s, h1s, l1s, h2s, l2s, h3s, l3s;
    split_bits2(n0v, h0s, l0s); split_bits2(n1v, h1s, l1s);
    split_bits2(n2v, h2s, l2s); split_bits2(n3v, h3s, l3s);
    bf16x4s hb, lb;
    hb[0] = h0s; hb[1] = h1s; hb[2] = h2s; hb[3] = h3s;
    lb[0] = l0s; lb[1] = l1s; lb[2] = l2s; lb[3] = l3s;
    *(bf16x4s*)(oh + g) = hb;
    *(bf16x4s*)(ol + g) = lb;
  }
}

// ---------------------------------------------------------------------------
// Pooling (deterministic) + classifier
// ---------------------------------------------------------------------------
__global__ __launch_bounds__(256) void pool_partial(const float* __restrict__ fn,
    float* __restrict__ partial) {
  __shared__ float red[256];
  int b = blockIdx.x, c = blockIdx.y;
  int tid = threadIdx.x;
  int d = tid & 127, rp_ = tid >> 7;
  float s = 0.f;
  size_t base = (size_t)b * LL + c * 256;
  for (int i = 0; i < 128; i++) {
    int row = i * 2 + rp_;
    s += fn[(base + row) * DM + d];
  }
  red[tid] = s;
  __syncthreads();
  if (tid < 128) partial[((size_t)b * 8 + c) * 128 + tid] = red[tid] + red[tid + 128];
}

__global__ void pool_reduce(const float* __restrict__ partial,
    float* __restrict__ pooled) {
  int idx = blockIdx.x * 256 + threadIdx.x;   // 2048
  int b = idx >> 7, d = idx & 127;
  float s = 0.f;
#pragma unroll
  for (int c = 0; c < 8; c++) s += partial[((size_t)b * 8 + c) * 128 + d];
  pooled[idx] = s * (1.f / LL);
}

__global__ void cls_kernel(const float* __restrict__ pooled,
    const float* __restrict__ cw, const float* __restrict__ cb,
    float* __restrict__ out) {
  int t = threadIdx.x;
  if (t < 80) {
    int b = t / 5, c = t % 5;
    float acc = cb[c];
    for (int d = 0; d < DM; d++) acc += pooled[b * DM + d] * cw[c * DM + d];
    out[t] = acc;
  }
}

// ---------------------------------------------------------------------------
extern "C" void kernel_launch(void* const* d_in, const int* in_sizes, int n_in,
                              void* d_out, int out_size, void* d_ws, size_t ws_size,
                              hipStream_t stream) {
  const float* x         = (const float*)d_in[0];
  const float* enc_w     = (const float*)d_in[1];
  const float* enc_b     = (const float*)d_in[2];
  const float* norm_w    = (const float*)d_in[3];
  const float* in_proj_w = (const float*)d_in[4];
  const float* conv_w    = (const float*)d_in[5];
  const float* conv_b    = (const float*)d_in[6];
  const float* x_proj_w  = (const float*)d_in[7];
  const float* dt_proj_w = (const float*)d_in[8];
  const float* dt_proj_b = (const float*)d_in[9];
  const float* A_log     = (const float*)d_in[10];
  const float* Dp        = (const float*)d_in[11];
  const float* out_proj_w= (const float*)d_in[12];
  const float* norm_f_w  = (const float*)d_in[13];
  const float* cls_w     = (const float*)d_in[14];
  const float* cls_b     = (const float*)d_in[15];
  float* out = (float*)d_out;

  float* ws = (float*)d_ws;
  float* h       = ws;                       // 4,194,304
  float* xdbl    = ws + 4194304;             // 2,097,152
  float* sega    = ws + 6291456;             // 4,194,304
  float* segh    = ws + 10485760;            // 4,194,304
  uint*  zs_pk   = (uint*)(ws + 14680064);   // 8,388,608
  uint*  u_pk    = (uint*)(ws + 23068672);   // 8,388,608
  uint*  xm_pk   = (uint*)(ws + 31457280);   // fnorm alias
  float* partial = ws + 39845888;            // 16,384
  float* pooled  = ws + 39862272;            // 2,048
  bf16* u0     = (bf16*)(ws + 39864320);
  bf16* xn_hi  = u0;                         // MP*128
  bf16* xn_lo  = u0 + 4194304;
  bf16* wip_hi = u0 + 8388608;               // 262,144
  bf16* wip_lo = wip_hi + 262144;
  bf16* wxp_hi = wip_lo + 262144;            // 65,536 (padded)
  bf16* wxp_lo = wxp_hi + 65536;
  bf16* wop_hi = wxp_lo + 65536;             // 131,072
  bf16* wop_lo = wop_hi + 131072;
  float* fnorm = (float*)xm_pk;

  split_w<<<1024, 256, 0, stream>>>(in_proj_w, wip_hi, wip_lo, 262144);
  split_w_pad<<<256, 256, 0, stream>>>(x_proj_w, wxp_hi, wxp_lo);
  split_w<<<512, 256, 0, stream>>>(out_proj_w, wop_hi, wop_lo, 131072);

  enc_norm_kernel<<<MP / 4, 256, 0, stream>>>(x, enc_w, enc_b, norm_w, h,
                                              xn_hi, xn_lo);

  for (int i = 0; i < 4; i++) {
    gemm_inproj_conv<<<MP / 32, 256, 0, stream>>>(xn_hi, xn_lo,
        wip_hi + i * 65536, wip_lo + i * 65536,
        wxp_hi + i * 16384, wxp_lo + i * 16384,
        conv_w + i * DI * 4, conv_b + i * DI,
        dt_proj_w + i * 2048, dt_proj_b + i * DI, A_log + i * DI * DS,
        zs_pk, u_pk, xdbl, sega, segh);
    scan_combine<<<256, 256, 0, stream>>>(sega, segh);
    scan2_outproj<<<dim3(NSEG, BB), 256, 0, stream>>>(u_pk, zs_pk, xdbl,
        dt_proj_w + i * 2048, dt_proj_b + i * DI, A_log + i * DI * DS,
        Dp + i * DI, sega, wop_hi + i * 32768, wop_lo + i * 32768, h,
        (i < 3) ? norm_w + (i + 1) * DM : norm_f_w,
        (i < 3) ? nullptr : fnorm, xn_hi, xn_lo);
  }

  pool_partial<<<dim3(BB, 8), 256, 0, stream>>>(fnorm, partial);
  pool_reduce<<<8, 256, 0, stream>>>(partial, pooled);
  cls_kernel<<<1, 128, 0, stream>>>(pooled, cls_w, cls_b, out);
}

// Round 14
// 629.848 us; speedup vs baseline: 1.2055x; 1.0039x over previous
//
#include <hip/hip_runtime.h>
#include <hip/hip_bf16.h>
#include <cstddef>

#define BB 16
#define LL 2048
#define DM 128
#define DI 256
#define DS 16
#define MP (BB*LL)          // 32768 positions
#define NSEG 64
#define SEGLEN (LL/NSEG)    // 32
#define YSTR 240            // ybuf LDS row stride (shorts): 480B rows, 16B-aligned
#define XSTR 40             // sx LDS row stride (floats) for scan2

typedef __attribute__((ext_vector_type(8))) short bf16x8;
typedef __attribute__((ext_vector_type(4))) short bf16x4s;
typedef __attribute__((ext_vector_type(8))) unsigned int ux8;
typedef __attribute__((ext_vector_type(4))) float f32x4;
typedef __hip_bfloat16 bf16;
typedef unsigned int uint;

__device__ inline void bf16split(float x, bf16& h, bf16& l) {
  h = __float2bfloat16(x);
  l = __float2bfloat16(x - __bfloat162float(h));
}
__device__ inline float bf2f(bf16 v) { return __bfloat162float(v); }
__device__ inline void split_bits2(float x, short& hs, short& ls) {
  bf16 hb = __float2bfloat16(x);
  bf16 lb = __float2bfloat16(x - __bfloat162float(hb));
  hs = *(short*)&hb;
  ls = *(short*)&lb;
}
__device__ inline short bfbits(float x) {
  bf16 b = __float2bfloat16(x);
  return *(short*)&b;
}
__device__ inline float sigm(float x) {
  return __builtin_amdgcn_rcpf(1.f + __expf(-x));
}
__device__ inline uint pk2(short h, short l) {
  return (uint)(unsigned short)h | ((uint)(unsigned short)l << 16);
}
__device__ inline uint pack_hl(float x) {
  short hs, ls; split_bits2(x, hs, ls);
  return pk2(hs, ls);
}
__device__ inline float unpack_hl(uint w) {
  return __uint_as_float(w << 16) + __uint_as_float(w & 0xffff0000u);
}

// ---------------------------------------------------------------------------
// Scan helpers (shared)
// ---------------------------------------------------------------------------
__device__ inline float softplus_f(float a) {
  float r = __logf(1.f + __expf(a));
  return a > 15.f ? a : r;
}

__device__ inline void make_powers(float r, float* rp) {
  rp[0] = r;
#pragma unroll
  for (int n = 1; n < 16; n++) {
    int a = (n + 1) >> 1, b = (n + 1) - a;
    rp[n] = rp[a - 1] * rp[b - 1];
  }
}

__device__ inline bool a_is_integer(const float* A_log, int d) {
  bool ok = true;
#pragma unroll
  for (int n = 0; n < DS; n++) {
    float Ad = -__expf(A_log[d * DS + n]);
    ok = ok && (fabsf(Ad + (float)(n + 1)) < 1e-3f);
  }
  return ok;
}

// ---------------------------------------------------------------------------
// Phase D body (fused kernel): scan1 with u from LDS buf (packed uint at
// buf[t*260+d], same bits as u_pk) and x from LDS sxp (24 cols: dt 0..7 +
// B 8..23 — scan1 never reads the C cols). Verbatim scan1 arithmetic.
// ---------------------------------------------------------------------------
template<bool FAST>
__device__ inline void scan1_lds2(int s, int b, int d,
    const float* sxp, const uint* buf,
    const float* __restrict__ dtw, const float* __restrict__ dtb,
    const float* __restrict__ A_log,
    float* __restrict__ sega, float* __restrict__ segh) {
  float wdt[8];
#pragma unroll
  for (int j = 0; j < 8; j++) wdt[j] = dtw[d * 8 + j];
  float bdt = dtb[d];
  float h[DS];
#pragma unroll
  for (int n = 0; n < DS; n++) h[n] = 0.f;
  float R = 1.f;
  float ap[DS];
  if (!FAST) {
#pragma unroll
    for (int n = 0; n < DS; n++) ap[n] = 1.f;
  }
#pragma unroll 4
  for (int t = 0; t < SEGLEN; t++) {
    const float* xr = sxp + t * 24;
    float dt = bdt;
#pragma unroll
    for (int j = 0; j < 8; j++) dt += xr[j] * wdt[j];
    float dl = softplus_f(dt);
    float u = unpack_hl(buf[t * 260 + d]);
    float du = dl * u;
    if (FAST) {
      float rp[DS];
      make_powers(__expf(-dl), rp);
      R *= rp[0];
#pragma unroll
      for (int n = 0; n < DS; n++) h[n] = fmaf(rp[n], h[n], du * xr[8 + n]);
    } else {
#pragma unroll
      for (int n = 0; n < DS; n++) {
        float dA = __expf(dl * (-__expf(A_log[d * DS + n])));
        h[n] = fmaf(dA, h[n], du * xr[8 + n]);
        ap[n] *= dA;
      }
    }
  }
  if (FAST) make_powers(R, ap);
  size_t o = ((size_t)s * 4096 + b * 256 + d) * DS;
#pragma unroll
  for (int j = 0; j < 4; j++) {
    *(float4*)(sega + o + 4 * j) = make_float4(ap[4*j], ap[4*j+1], ap[4*j+2], ap[4*j+3]);
    *(float4*)(segh + o + 4 * j) = make_float4(h[4*j], h[4*j+1], h[4*j+2], h[4*j+3]);
  }
}

// ---------------------------------------------------------------------------
// Fused kernel: exact R10/R13 form (champion). R9/R11/R12 proved the phase-A
// register footprint cannot be capped/split without spill or re-read costs —
// lever retired. u aliased in-place into xmb cells; sx in dead rows 32..34.
// ---------------------------------------------------------------------------
__global__ __launch_bounds__(256, 2) void gemm_inproj_conv(
    const bf16* __restrict__ Ah, const bf16* __restrict__ Al,
    const bf16* __restrict__ Wh, const bf16* __restrict__ Wl,   // in_proj [512][128]
    const bf16* __restrict__ Xh, const bf16* __restrict__ Xl,   // x_proj padded [64][256]
    const float* __restrict__ cw, const float* __restrict__ cb,
    const float* __restrict__ dtw, const float* __restrict__ dtb,
    const float* __restrict__ A_log,
    uint* __restrict__ zs_pk, uint* __restrict__ u_pk,
    float* __restrict__ C,
    float* __restrict__ sega, float* __restrict__ segh) {
  __shared__ uint buf[35 * 260];         // 36,400 B: xm rows -> u rows (in-place) + sx tail
  int tid = threadIdx.x;
  int wave = tid >> 6, lane = tid & 63;
  int r16 = lane & 15, quad = lane >> 4;
  int m0 = blockIdx.x * 32;

  // ---- phase A: in_proj GEMM. A rows m0-16..m0+31 (3 row-tiles, clamped).
  size_t arow[3];
#pragma unroll
  for (int rt = 0; rt < 3; rt++) {
    int rg = m0 - 16 + rt * 16 + r16;
    if (rg < 0) rg = 0;                  // garbage rows are conv-masked
    arow[rt] = (size_t)rg * DM + quad * 8;
  }
  size_t browx[4], browz[4];
#pragma unroll
  for (int ct = 0; ct < 4; ct++) {
    browx[ct] = (size_t)(wave * 64 + ct * 16 + r16) * DM + quad * 8;
    browz[ct] = (size_t)(256 + wave * 64 + ct * 16 + r16) * DM + quad * 8;
  }
  f32x4 accx[3][4] = {};
  f32x4 accz[2][4] = {};
#pragma unroll
  for (int kk = 0; kk < 4; kk++) {
    int ko = kk * 32;
    bf16x8 ah[3], al[3], bxh[4], bxl[4], bzh[4], bzl[4];
#pragma unroll
    for (int rt = 0; rt < 3; rt++) {
      ah[rt] = *(const bf16x8*)(Ah + arow[rt] + ko);
      al[rt] = *(const bf16x8*)(Al + arow[rt] + ko);
    }
#pragma unroll
    for (int ct = 0; ct < 4; ct++) {
      bxh[ct] = *(const bf16x8*)(Wh + browx[ct] + ko);
      bxl[ct] = *(const bf16x8*)(Wl + browx[ct] + ko);
      bzh[ct] = *(const bf16x8*)(Wh + browz[ct] + ko);
      bzl[ct] = *(const bf16x8*)(Wl + browz[ct] + ko);
    }
#pragma unroll
    for (int rt = 0; rt < 3; rt++)
#pragma unroll
      for (int ct = 0; ct < 4; ct++) {
        accx[rt][ct] = __builtin_amdgcn_mfma_f32_16x16x32_bf16(ah[rt], bxh[ct], accx[rt][ct], 0, 0, 0);
        accx[rt][ct] = __builtin_amdgcn_mfma_f32_16x16x32_bf16(ah[rt], bxl[ct], accx[rt][ct], 0, 0, 0);
        accx[rt][ct] = __builtin_amdgcn_mfma_f32_16x16x32_bf16(al[rt], bxh[ct], accx[rt][ct], 0, 0, 0);
      }
#pragma unroll
    for (int rz = 0; rz < 2; rz++)
#pragma unroll
      for (int ct = 0; ct < 4; ct++) {
        accz[rz][ct] = __builtin_amdgcn_mfma_f32_16x16x32_bf16(ah[rz + 1], bzh[ct], accz[rz][ct], 0, 0, 0);
        accz[rz][ct] = __builtin_amdgcn_mfma_f32_16x16x32_bf16(ah[rz + 1], bzl[ct], accz[rz][ct], 0, 0, 0);
        accz[rz][ct] = __builtin_amdgcn_mfma_f32_16x16x32_bf16(al[rz + 1], bzh[ct], accz[rz][ct], 0, 0, 0);
      }
  }
  // zs epilogue (identical expression: v *= sigm(v); pack_hl)
#pragma unroll
  for (int rz = 0; rz < 2; rz++)
#pragma unroll
    for (int ct = 0; ct < 4; ct++)
#pragma unroll
      for (int r = 0; r < 4; r++) {
        int row = m0 + rz * 16 + quad * 4 + r;
        int col = wave * 64 + ct * 16 + r16;
        float v = accz[rz][ct][r];
        v *= sigm(v);
        zs_pk[(size_t)row * DI + col] = pack_hl(v);
      }
  // xm -> LDS packed (rows m0-3..m0+31 => lidx 0..34)
#pragma unroll
  for (int rt = 0; rt < 3; rt++)
#pragma unroll
    for (int ct = 0; ct < 4; ct++)
#pragma unroll
      for (int r = 0; r < 4; r++) {
        int lidx = rt * 16 + quad * 4 + r - 13;
        if (lidx >= 0)
          buf[lidx * 260 + wave * 64 + ct * 16 + r16] = pack_hl(accx[rt][ct][r]);
      }
  __syncthreads();

  // ---- phase B: conv + SiLU. Thread d: channel d over 32 rows. Writes the
  // packed u IN-PLACE into buf[t][d] (cell read by the same thread at step
  // t-3, or pre-loop for t<3 => per-thread read-before-write, race-free).
  {
    int d = tid;
    float4 w4 = *(const float4*)(cw + d * 4);
    float w0 = w4.x, w1 = w4.y, w2 = w4.z, w3 = w4.w;
    float bias = cb[d];
    float xa = unpack_hl(buf[0 * 260 + d]);
    float xb = unpack_hl(buf[1 * 260 + d]);
    float xc = unpack_hl(buf[2 * 260 + d]);
    int lbase = m0 & (LL - 1);
#pragma unroll 4
    for (int t = 0; t < 32; t++) {
      float xd = unpack_hl(buf[(t + 3) * 260 + d]);
      int l = lbase + t;
      float x0 = xa * ((l >= 3) ? 1.f : 0.f);
      float x1 = xb * ((l >= 2) ? 1.f : 0.f);
      float x2 = xc * ((l >= 1) ? 1.f : 0.f);
      float c0 = bias + w0 * x0 + w1 * x1 + w2 * x2 + w3 * xd;
      float u = c0 * sigm(c0);
      short hs, ls; split_bits2(u, hs, ls);
      uint up = pk2(hs, ls);
      u_pk[(size_t)(m0 + t) * DI + d] = up;
      buf[t * 260 + d] = up;
      xa = xb; xb = xc; xc = xd;
    }
  }
  __syncthreads();   // u rows 0..31 complete in buf; rows 32..34 dead -> sx

  // ---- phase C: x_proj GEMM. 6 tiles over 4 waves; A-frags unpacked from
  // LDS u (same bits as old ubh/ubl). Results -> global C; cols 0..23 also
  // -> LDS sxp (rows 32..34 region, stride 24) for phase D.
  float* sxp = (float*)(buf + 32 * 260);   // 768 floats <= 780 free
  {
    int rt0 = (wave == 3) ? 1 : 0;
    int ct0 = (wave == 0) ? 0 : (wave == 1) ? 1 : (wave == 2) ? 2 : 0;
#pragma unroll 1
    for (int tt = 0; tt < 2; tt++) {
      int rt, ct;
      if (tt == 0) { rt = rt0; ct = ct0; }
      else { if (wave >= 2) break; rt = 1; ct = wave + 1; }
      f32x4 a2 = {};
#pragma unroll
      for (int kk = 0; kk < 8; kk++) {
        int k0 = quad * 8 + kk * 32;
        const uint* ub = buf + (rt * 16 + r16) * 260 + k0;
        bf16x8 ahh, alo;
#pragma unroll
        for (int e = 0; e < 8; e++) {
          uint w = ub[e];
          ahh[e] = (short)(w & 0xffffu);
          alo[e] = (short)(w >> 16);
        }
        size_t br = (size_t)(ct * 16 + r16) * DI + quad * 8 + kk * 32;
        bf16x8 bhh = *(const bf16x8*)(Xh + br);
        bf16x8 blo = *(const bf16x8*)(Xl + br);
        a2 = __builtin_amdgcn_mfma_f32_16x16x32_bf16(ahh, bhh, a2, 0, 0, 0);
        a2 = __builtin_amdgcn_mfma_f32_16x16x32_bf16(ahh, blo, a2, 0, 0, 0);
        a2 = __builtin_amdgcn_mfma_f32_16x16x32_bf16(alo, bhh, a2, 0, 0, 0);
      }
#pragma unroll
      for (int r = 0; r < 4; r++) {
        int row = rt * 16 + quad * 4 + r;
        int col = ct * 16 + r16;
        C[(size_t)(m0 + row) * 64 + col] = a2[r];
        if (col < 24) sxp[row * 24 + col] = a2[r];
      }
    }
  }
  __syncthreads();

  // ---- phase D: scan_phase1; u + x both from LDS. Thread d = channel d.
  {
    int b = blockIdx.x >> 6, s = blockIdx.x & 63, d = tid;
    if (a_is_integer(A_log, d))
      scan1_lds2<true>(s, b, d, sxp, buf, dtw, dtb, A_log, sega, segh);
    else
      scan1_lds2<false>(s, b, d, sxp, buf, dtw, dtb, A_log, sega, segh);
  }
}

// ---------------------------------------------------------------------------
// FUSED encoder + RMSNorm (layer-0 prologue), bitwise-identical.
// ---------------------------------------------------------------------------
__global__ __launch_bounds__(256) void enc_norm_kernel(const float* __restrict__ x,
    const float* __restrict__ ew, const float* __restrict__ eb,
    const float* __restrict__ w, float* __restrict__ h,
    bf16* __restrict__ oh, bf16* __restrict__ ol) {
  int lane = threadIdx.x & 63;
  int pos = blockIdx.x * 4 + (threadIdx.x >> 6);
  const float* xr = x + (size_t)pos * 12;
  float v0 = eb[lane], v1 = eb[lane + 64];
#pragma unroll
  for (int c = 0; c < 12; c++) {
    float xv = xr[c];
    v0 += xv * ew[lane * 12 + c];
    v1 += xv * ew[(lane + 64) * 12 + c];
  }
  size_t o = (size_t)pos * DM;
  h[o + lane] = v0;
  h[o + lane + 64] = v1;
  float ss = v0 * v0 + v1 * v1;
#pragma unroll
  for (int off = 1; off < 64; off <<= 1) ss += __shfl_xor(ss, off);
  float sc = rsqrtf(ss * (1.f / DM) + 1e-5f);
  float a = v0 * sc * w[lane], b = v1 * sc * w[lane + 64];
  bf16split(a, oh[o + lane], ol[o + lane]);
  bf16split(b, oh[o + lane + 64], ol[o + lane + 64]);
}

// ---------------------------------------------------------------------------
// Weight splits
// ---------------------------------------------------------------------------
__global__ void split_w(const float* __restrict__ src, bf16* __restrict__ hi,
                        bf16* __restrict__ lo, int n) {
  int i = blockIdx.x * 256 + threadIdx.x;
  if (i < n) bf16split(src[i], hi[i], lo[i]);
}

__global__ void split_w_pad(const float* __restrict__ src, bf16* __restrict__ hi,
                            bf16* __restrict__ lo) {
  int i = blockIdx.x * 256 + threadIdx.x;   // < 4*64*256
  int l = i >> 14, rem = i & 16383, r = rem >> 8, k = rem & 255;
  float v = (r < 40) ? src[l * 10240 + r * 256 + k] : 0.f;
  bf16split(v, hi[i], lo[i]);
}

// load 32 rows x 40 cols of xdbl (cols 0..39) into LDS, stride XSTR
__device__ inline void load_sx(float* sx, const float* xdbl, size_t rbase, int tid) {
#pragma unroll
  for (int j = 0; j < 2; j++) {
    int idx = j * 256 + tid;       // < 320 = 32 rows x 10 float4
    if (idx < 320) {
      int row = idx / 10, c = idx % 10;
      *(float4*)(sx + row * XSTR + c * 4) = *(const float4*)(xdbl + rbase + row * 64 + c * 4);
    }
  }
}

// ---------------------------------------------------------------------------
// scan_combine, 65536 scalar chains over 256 blocks (every CU active).
// ---------------------------------------------------------------------------
__global__ __launch_bounds__(256) void scan_combine(float* __restrict__ sega,
    const float* __restrict__ segh) {
  int g = blockIdx.x * 256 + threadIdx.x;   // chain id = (b*256+d)*16+n
  float h0 = 0.f;
  for (int s = 0; s < NSEG; s++) {
    size_t q = (size_t)s * 65536 + g;
    float a = sega[q];
    float hh = segh[q];
    sega[q] = h0;
    h0 = a * h0 + hh;
  }
}

// ---------------------------------------------------------------------------
// scan2: FUSED scan_phase2 + out_proj + residual + RMSNorm.
// R14: LDS shaved 22,016 -> 20,480 B (= 160KB/8): YSTR 264->240 (480B rows,
// 16B-aligned; out_proj A-reads go 2-way -> 4-way bank aliasing on only 16
// ds_reads/wave) + unified smem so the fp32 tile (16,896 B) spans ybuf + the
// then-dead sx region. launch_bounds(256,8): VGPR cap 64 >= observed 36.
// All arithmetic and addressing expressions unchanged => bitwise-identical.
// ---------------------------------------------------------------------------
template<bool FAST>
__device__ inline void scan2_to_lds(int s, int b, int d, const float* sx,
    const uint* __restrict__ u_pk, const uint* __restrict__ zs_pk,
    const float* __restrict__ dtw, const float* __restrict__ dtb,
    const float* __restrict__ A_log, const float* __restrict__ Dp,
    const float* __restrict__ sega, short* __restrict__ ybuf) {
  float wdt[8];
#pragma unroll
  for (int j = 0; j < 8; j++) wdt[j] = dtw[d * 8 + j];
  float bdt = dtb[d];
  float h[DS];
  size_t o = ((size_t)s * 4096 + b * 256 + d) * DS;
#pragma unroll
  for (int n = 0; n < DS; n++) h[n] = sega[o + n];
  float Dd = Dp[d];
  size_t base = (size_t)b * LL + (size_t)s * SEGLEN;
  const uint* up = u_pk + base * DI + d;
  const uint* zp = zs_pk + base * DI + d;
  uint ub = *up, zb = *zp;
#pragma unroll 4
  for (int t = 0; t < SEGLEN; t++) {
    up += DI; zp += DI;
    uint ub_next = *up;
    uint zb_next = *zp;
    const float* xr = sx + t * XSTR;
    float dt = bdt;
#pragma unroll
    for (int j = 0; j < 8; j++) dt += xr[j] * wdt[j];
    float dl = softplus_f(dt);
    float u = unpack_hl(ub);
    float du = dl * u;
    float acc = 0.f;
    if (FAST) {
      float rp[DS];
      make_powers(__expf(-dl), rp);
#pragma unroll
      for (int n = 0; n < DS; n++) {
        h[n] = fmaf(rp[n], h[n], du * xr[8 + n]);
        acc = fmaf(h[n], xr[24 + n], acc);
      }
    } else {
#pragma unroll
      for (int n = 0; n < DS; n++) {
        float dA = __expf(dl * (-__expf(A_log[d * DS + n])));
        h[n] = fmaf(dA, h[n], du * xr[8 + n]);
        acc = fmaf(h[n], xr[24 + n], acc);
      }
    }
    float zs = unpack_hl(zb);
    float yv = (acc + u * Dd) * zs;
    ybuf[t * YSTR + d] = bfbits(yv);
    ub = ub_next; zb = zb_next;
  }
}

__global__ __launch_bounds__(256, 8) void scan2_outproj(
    const uint* __restrict__ u_pk, const uint* __restrict__ zs_pk,
    const float* __restrict__ xdbl, const float* __restrict__ dtw,
    const float* __restrict__ dtb, const float* __restrict__ A_log,
    const float* __restrict__ Dp, const float* __restrict__ sega,
    const bf16* __restrict__ Wh, const bf16* __restrict__ Wl,
    float* __restrict__ hbuf, const float* __restrict__ nw,
    float* __restrict__ of, bf16* __restrict__ oh, bf16* __restrict__ ol) {
  __shared__ float smem[5120];             // 20,480 B total
  short* ybuf = (short*)smem;              // 32 x YSTR(240) shorts = 15,360 B
  float* sx   = smem + 3840;               // 32 x XSTR(40) floats =  5,120 B
  int s = blockIdx.x, b = blockIdx.y;
  int tid = threadIdx.x, d = tid;
  size_t rbase = ((size_t)b * LL + (size_t)s * SEGLEN) * 64;
  load_sx(sx, xdbl, rbase, tid);
  __syncthreads();
  if (a_is_integer(A_log, d))
    scan2_to_lds<true>(s, b, d, sx, u_pk, zs_pk, dtw, dtb, A_log, Dp, sega, ybuf);
  else
    scan2_to_lds<false>(s, b, d, sx, u_pk, zs_pk, dtw, dtb, A_log, Dp, sega, ybuf);
  __syncthreads();
  // out_proj: C[32x128] = y[32x256] @ Wop[128x256]^T, wave covers 32 cols
  int wave = tid >> 6, lane = tid & 63;
  int r16 = lane & 15, quad = lane >> 4;
  int n0 = wave * 32;
  size_t brow[2];
#pragma unroll
  for (int j = 0; j < 2; j++)
    brow[j] = (size_t)(n0 + j * 16 + r16) * DI + quad * 8;
  f32x4 acc[2][2] = {};
#pragma unroll
  for (int kk = 0; kk < 8; kk++) {
    int k0 = quad * 8 + kk * 32;
    bf16x8 ah[2], bh[2], bl[2];
#pragma unroll
    for (int i = 0; i < 2; i++)
      ah[i] = *(const bf16x8*)(ybuf + (i * 16 + r16) * YSTR + k0);
#pragma unroll
    for (int j = 0; j < 2; j++) {
      bh[j] = *(const bf16x8*)(Wh + brow[j] + kk * 32);
      bl[j] = *(const bf16x8*)(Wl + brow[j] + kk * 32);
    }
#pragma unroll
    for (int i = 0; i < 2; i++)
#pragma unroll
      for (int j = 0; j < 2; j++) {
        acc[i][j] = __builtin_amdgcn_mfma_f32_16x16x32_bf16(ah[i], bh[j], acc[i][j], 0, 0, 0);
        acc[i][j] = __builtin_amdgcn_mfma_f32_16x16x32_bf16(ah[i], bl[j], acc[i][j], 0, 0, 0);
      }
  }
  __syncthreads();   // all LDS y reads done; sx also dead; reuse smem as
  float* tile = smem;   // fp32 tile 32x132 = 16,896 B <= 20,480 B
#pragma unroll
  for (int i = 0; i < 2; i++)
#pragma unroll
    for (int j = 0; j < 2; j++)
#pragma unroll
      for (int r = 0; r < 4; r++) {
        int rl = i * 16 + quad * 4 + r;
        int col = n0 + j * 16 + r16;
        tile[rl * 132 + col] = acc[i][j][r];
      }
  __syncthreads();
  // epilogue: residual + rmsnorm + bf16 split, coalesced
  size_t mbase = (size_t)b * LL + (size_t)s * SEGLEN;
#pragma unroll
  for (int it = 0; it < 4; it++) {
    int idx = it * 256 + tid;
    int row = idx >> 5, c4 = idx & 31;
    size_t g = (mbase + row) * DM + c4 * 4;
    float4 hv = *(float4*)(hbuf + g);
    const float* tp = tile + row * 132 + c4 * 4;
    float4 v = make_float4(tp[0] + hv.x, tp[1] + hv.y, tp[2] + hv.z, tp[3] + hv.w);
    *(float4*)(hbuf + g) = v;
    float ss = v.x * v.x + v.y * v.y + v.z * v.z + v.w * v.w;
    ss += __shfl_xor(ss, 1);
    ss += __shfl_xor(ss, 2);
    ss += __shfl_xor(ss, 4);
    ss += __shfl_xor(ss, 8);
    ss += __shfl_xor(ss, 16);
    float sc = rsqrtf(ss * (1.f / DM) + 1e-5f);
    float4 w4 = *(const float4*)(nw + c4 * 4);
    float n0v = v.x * sc * w4.x, n1v = v.y * sc * w4.y;
    float n2v = v.z * sc * w4.z, n3v = v.w * sc * w4.w;
    if (of) *(float4*)(of + g) = make_float4(n0v, n1v, n2v, n3v);
    short h0s, l0s, h1s, l1s, h2s, l2s, h3s, l3s;
    split_bits2(n0v, h0s, l0s); split_bits2(n1v, h1s, l1s);
    split_bits2(n2v, h2s, l2s); split_bits2(n3v, h3s, l3s);
    bf16x4s hb, lb;
    hb[0] = h0s; hb[1] = h1s; hb[2] = h2s; hb[3] = h3s;
    lb[0] = l0s; lb[1] = l1s; lb[2] = l2s; lb[3] = l3s;
    *(bf16x4s*)(oh + g) = hb;
    *(bf16x4s*)(ol + g) = lb;
  }
}

// ---------------------------------------------------------------------------
// Pooling (deterministic) + classifier
// ---------------------------------------------------------------------------
__global__ __launch_bounds__(256) void pool_partial(const float* __restrict__ fn,
    float* __restrict__ partial) {
  __shared__ float red[256];
  int b = blockIdx.x, c = blockIdx.y;
  int tid = threadIdx.x;
  int d = tid & 127, rp_ = tid >> 7;
  float s = 0.f;
  size_t base = (size_t)b * LL + c * 256;
  for (int i = 0; i < 128; i++) {
    int row = i * 2 + rp_;
    s += fn[(base + row) * DM + d];
  }
  red[tid] = s;
  __syncthreads();
  if (tid < 128) partial[((size_t)b * 8 + c) * 128 + tid] = red[tid] + red[tid + 128];
}

__global__ void pool_reduce(const float* __restrict__ partial,
    float* __restrict__ pooled) {
  int idx = blockIdx.x * 256 + threadIdx.x;   // 2048
  int b = idx >> 7, d = idx & 127;
  float s = 0.f;
#pragma unroll
  for (int c = 0; c < 8; c++) s += partial[((size_t)b * 8 + c) * 128 + d];
  pooled[idx] = s * (1.f / LL);
}

__global__ void cls_kernel(const float* __restrict__ pooled,
    const float* __restrict__ cw, const float* __restrict__ cb,
    float* __restrict__ out) {
  int t = threadIdx.x;
  if (t < 80) {
    int b = t / 5, c = t % 5;
    float acc = cb[c];
    for (int d = 0; d < DM; d++) acc += pooled[b * DM + d] * cw[c * DM + d];
    out[t] = acc;
  }
}

// ---------------------------------------------------------------------------
extern "C" void kernel_launch(void* const* d_in, const int* in_sizes, int n_in,
                              void* d_out, int out_size, void* d_ws, size_t ws_size,
                              hipStream_t stream) {
  const float* x         = (const float*)d_in[0];
  const float* enc_w     = (const float*)d_in[1];
  const float* enc_b     = (const float*)d_in[2];
  const float* norm_w    = (const float*)d_in[3];
  const float* in_proj_w = (const float*)d_in[4];
  const float* conv_w    = (const float*)d_in[5];
  const float* conv_b    = (const float*)d_in[6];
  const float* x_proj_w  = (const float*)d_in[7];
  const float* dt_proj_w = (const float*)d_in[8];
  const float* dt_proj_b = (const float*)d_in[9];
  const float* A_log     = (const float*)d_in[10];
  const float* Dp        = (const float*)d_in[11];
  const float* out_proj_w= (const float*)d_in[12];
  const float* norm_f_w  = (const float*)d_in[13];
  const float* cls_w     = (const float*)d_in[14];
  const float* cls_b     = (const float*)d_in[15];
  float* out = (float*)d_out;

  float* ws = (float*)d_ws;
  float* h       = ws;                       // 4,194,304
  float* xdbl    = ws + 4194304;             // 2,097,152
  float* sega    = ws + 6291456;             // 4,194,304
  float* segh    = ws + 10485760;            // 4,194,304
  uint*  zs_pk   = (uint*)(ws + 14680064);   // 8,388,608
  uint*  u_pk    = (uint*)(ws + 23068672);   // 8,388,608
  uint*  xm_pk   = (uint*)(ws + 31457280);   // fnorm alias
  float* partial = ws + 39845888;            // 16,384
  float* pooled  = ws + 39862272;            // 2,048
  bf16* u0     = (bf16*)(ws + 39864320);
  bf16* xn_hi  = u0;                         // MP*128
  bf16* xn_lo  = u0 + 4194304;
  bf16* wip_hi = u0 + 8388608;               // 262,144
  bf16* wip_lo = wip_hi + 262144;
  bf16* wxp_hi = wip_lo + 262144;            // 65,536 (padded)
  bf16* wxp_lo = wxp_hi + 65536;
  bf16* wop_hi = wxp_lo + 65536;             // 131,072
  bf16* wop_lo = wop_hi + 131072;
  float* fnorm = (float*)xm_pk;

  split_w<<<1024, 256, 0, stream>>>(in_proj_w, wip_hi, wip_lo, 262144);
  split_w_pad<<<256, 256, 0, stream>>>(x_proj_w, wxp_hi, wxp_lo);
  split_w<<<512, 256, 0, stream>>>(out_proj_w, wop_hi, wop_lo, 131072);

  enc_norm_kernel<<<MP / 4, 256, 0, stream>>>(x, enc_w, enc_b, norm_w, h,
                                              xn_hi, xn_lo);

  for (int i = 0; i < 4; i++) {
    gemm_inproj_conv<<<MP / 32, 256, 0, stream>>>(xn_hi, xn_lo,
        wip_hi + i * 65536, wip_lo + i * 65536,
        wxp_hi + i * 16384, wxp_lo + i * 16384,
        conv_w + i * DI * 4, conv_b + i * DI,
        dt_proj_w + i * 2048, dt_proj_b + i * DI, A_log + i * DI * DS,
        zs_pk, u_pk, xdbl, sega, segh);
    scan_combine<<<256, 256, 0, stream>>>(sega, segh);
    scan2_outproj<<<dim3(NSEG, BB), 256, 0, stream>>>(u_pk, zs_pk, xdbl,
        dt_proj_w + i * 2048, dt_proj_b + i * DI, A_log + i * DI * DS,
        Dp + i * DI, sega, wop_hi + i * 32768, wop_lo + i * 32768, h,
        (i < 3) ? norm_w + (i + 1) * DM : norm_f_w,
        (i < 3) ? nullptr : fnorm, xn_hi, xn_lo);
  }

  pool_partial<<<dim3(BB, 8), 256, 0, stream>>>(fnorm, partial);
  pool_reduce<<<8, 256, 0, stream>>>(partial, pooled);
  cls_kernel<<<1, 128, 0, stream>>>(pooled, cls_w, cls_b, out);
}

// Round 15
// 624.598 us; speedup vs baseline: 1.2156x; 1.0084x over previous
//
#include <hip/hip_runtime.h>
#include <hip/hip_bf16.h>
#include <cstddef>

#define BB 16
#define LL 2048
#define DM 128
#define DI 256
#define DS 16
#define MP (BB*LL)          // 32768 positions
#define NSEG 64
#define SEGLEN (LL/NSEG)    // 32
#define YSTR 264            // ybuf LDS row stride (shorts): >=256+pad, 16B-aligned rows
#define XSTR 40             // sx LDS row stride (floats) for scan2

typedef __attribute__((ext_vector_type(8))) short bf16x8;
typedef __attribute__((ext_vector_type(4))) short bf16x4s;
typedef __attribute__((ext_vector_type(8))) unsigned int ux8;
typedef __attribute__((ext_vector_type(4))) float f32x4;
typedef __hip_bfloat16 bf16;
typedef unsigned int uint;

__device__ inline void bf16split(float x, bf16& h, bf16& l) {
  h = __float2bfloat16(x);
  l = __float2bfloat16(x - __bfloat162float(h));
}
__device__ inline float bf2f(bf16 v) { return __bfloat162float(v); }
__device__ inline void split_bits2(float x, short& hs, short& ls) {
  bf16 hb = __float2bfloat16(x);
  bf16 lb = __float2bfloat16(x - __bfloat162float(hb));
  hs = *(short*)&hb;
  ls = *(short*)&lb;
}
__device__ inline short bfbits(float x) {
  bf16 b = __float2bfloat16(x);
  return *(short*)&b;
}
__device__ inline float sigm(float x) {
  return __builtin_amdgcn_rcpf(1.f + __expf(-x));
}
__device__ inline uint pk2(short h, short l) {
  return (uint)(unsigned short)h | ((uint)(unsigned short)l << 16);
}
__device__ inline uint pack_hl(float x) {
  short hs, ls; split_bits2(x, hs, ls);
  return pk2(hs, ls);
}
__device__ inline float unpack_hl(uint w) {
  return __uint_as_float(w << 16) + __uint_as_float(w & 0xffff0000u);
}

// ---------------------------------------------------------------------------
// Scan helpers (shared)
// ---------------------------------------------------------------------------
__device__ inline float softplus_f(float a) {
  float r = __logf(1.f + __expf(a));
  return a > 15.f ? a : r;
}

__device__ inline void make_powers(float r, float* rp) {
  rp[0] = r;
#pragma unroll
  for (int n = 1; n < 16; n++) {
    int a = (n + 1) >> 1, b = (n + 1) - a;
    rp[n] = rp[a - 1] * rp[b - 1];
  }
}

__device__ inline bool a_is_integer(const float* A_log, int d) {
  bool ok = true;
#pragma unroll
  for (int n = 0; n < DS; n++) {
    float Ad = -__expf(A_log[d * DS + n]);
    ok = ok && (fabsf(Ad + (float)(n + 1)) < 1e-3f);
  }
  return ok;
}

// ---------------------------------------------------------------------------
// Phase D body (fused kernel): scan1 with u from LDS buf (packed uint at
// buf[t*260+d], same bits as u_pk) and x from LDS sxp (24 cols: dt 0..7 +
// B 8..23 — scan1 never reads the C cols). Verbatim scan1 arithmetic.
// ---------------------------------------------------------------------------
template<bool FAST>
__device__ inline void scan1_lds2(int s, int b, int d,
    const float* sxp, const uint* buf,
    const float* __restrict__ dtw, const float* __restrict__ dtb,
    const float* __restrict__ A_log,
    float* __restrict__ sega, float* __restrict__ segh) {
  float wdt[8];
#pragma unroll
  for (int j = 0; j < 8; j++) wdt[j] = dtw[d * 8 + j];
  float bdt = dtb[d];
  float h[DS];
#pragma unroll
  for (int n = 0; n < DS; n++) h[n] = 0.f;
  float R = 1.f;
  float ap[DS];
  if (!FAST) {
#pragma unroll
    for (int n = 0; n < DS; n++) ap[n] = 1.f;
  }
#pragma unroll 4
  for (int t = 0; t < SEGLEN; t++) {
    const float* xr = sxp + t * 24;
    float dt = bdt;
#pragma unroll
    for (int j = 0; j < 8; j++) dt += xr[j] * wdt[j];
    float dl = softplus_f(dt);
    float u = unpack_hl(buf[t * 260 + d]);
    float du = dl * u;
    if (FAST) {
      float rp[DS];
      make_powers(__expf(-dl), rp);
      R *= rp[0];
#pragma unroll
      for (int n = 0; n < DS; n++) h[n] = fmaf(rp[n], h[n], du * xr[8 + n]);
    } else {
#pragma unroll
      for (int n = 0; n < DS; n++) {
        float dA = __expf(dl * (-__expf(A_log[d * DS + n])));
        h[n] = fmaf(dA, h[n], du * xr[8 + n]);
        ap[n] *= dA;
      }
    }
  }
  if (FAST) make_powers(R, ap);
  size_t o = ((size_t)s * 4096 + b * 256 + d) * DS;
#pragma unroll
  for (int j = 0; j < 4; j++) {
    *(float4*)(sega + o + 4 * j) = make_float4(ap[4*j], ap[4*j+1], ap[4*j+2], ap[4*j+3]);
    *(float4*)(segh + o + 4 * j) = make_float4(h[4*j], h[4*j+1], h[4*j+2], h[4*j+3]);
  }
}

// ---------------------------------------------------------------------------
// Fused kernel: exact R10/R13 form (champion). R9/R11/R12 proved the phase-A
// register footprint cannot be capped/split without spill or re-read costs —
// lever retired. u aliased in-place into xmb cells; sx in dead rows 32..34.
// ---------------------------------------------------------------------------
__global__ __launch_bounds__(256, 2) void gemm_inproj_conv(
    const bf16* __restrict__ Ah, const bf16* __restrict__ Al,
    const bf16* __restrict__ Wh, const bf16* __restrict__ Wl,   // in_proj [512][128]
    const bf16* __restrict__ Xh, const bf16* __restrict__ Xl,   // x_proj padded [64][256]
    const float* __restrict__ cw, const float* __restrict__ cb,
    const float* __restrict__ dtw, const float* __restrict__ dtb,
    const float* __restrict__ A_log,
    uint* __restrict__ zs_pk, uint* __restrict__ u_pk,
    float* __restrict__ C,
    float* __restrict__ sega, float* __restrict__ segh) {
  __shared__ uint buf[35 * 260];         // 36,400 B: xm rows -> u rows (in-place) + sx tail
  int tid = threadIdx.x;
  int wave = tid >> 6, lane = tid & 63;
  int r16 = lane & 15, quad = lane >> 4;
  int m0 = blockIdx.x * 32;

  // ---- phase A: in_proj GEMM. A rows m0-16..m0+31 (3 row-tiles, clamped).
  size_t arow[3];
#pragma unroll
  for (int rt = 0; rt < 3; rt++) {
    int rg = m0 - 16 + rt * 16 + r16;
    if (rg < 0) rg = 0;                  // garbage rows are conv-masked
    arow[rt] = (size_t)rg * DM + quad * 8;
  }
  size_t browx[4], browz[4];
#pragma unroll
  for (int ct = 0; ct < 4; ct++) {
    browx[ct] = (size_t)(wave * 64 + ct * 16 + r16) * DM + quad * 8;
    browz[ct] = (size_t)(256 + wave * 64 + ct * 16 + r16) * DM + quad * 8;
  }
  f32x4 accx[3][4] = {};
  f32x4 accz[2][4] = {};
#pragma unroll
  for (int kk = 0; kk < 4; kk++) {
    int ko = kk * 32;
    bf16x8 ah[3], al[3], bxh[4], bxl[4], bzh[4], bzl[4];
#pragma unroll
    for (int rt = 0; rt < 3; rt++) {
      ah[rt] = *(const bf16x8*)(Ah + arow[rt] + ko);
      al[rt] = *(const bf16x8*)(Al + arow[rt] + ko);
    }
#pragma unroll
    for (int ct = 0; ct < 4; ct++) {
      bxh[ct] = *(const bf16x8*)(Wh + browx[ct] + ko);
      bxl[ct] = *(const bf16x8*)(Wl + browx[ct] + ko);
      bzh[ct] = *(const bf16x8*)(Wh + browz[ct] + ko);
      bzl[ct] = *(const bf16x8*)(Wl + browz[ct] + ko);
    }
#pragma unroll
    for (int rt = 0; rt < 3; rt++)
#pragma unroll
      for (int ct = 0; ct < 4; ct++) {
        accx[rt][ct] = __builtin_amdgcn_mfma_f32_16x16x32_bf16(ah[rt], bxh[ct], accx[rt][ct], 0, 0, 0);
        accx[rt][ct] = __builtin_amdgcn_mfma_f32_16x16x32_bf16(ah[rt], bxl[ct], accx[rt][ct], 0, 0, 0);
        accx[rt][ct] = __builtin_amdgcn_mfma_f32_16x16x32_bf16(al[rt], bxh[ct], accx[rt][ct], 0, 0, 0);
      }
#pragma unroll
    for (int rz = 0; rz < 2; rz++)
#pragma unroll
      for (int ct = 0; ct < 4; ct++) {
        accz[rz][ct] = __builtin_amdgcn_mfma_f32_16x16x32_bf16(ah[rz + 1], bzh[ct], accz[rz][ct], 0, 0, 0);
        accz[rz][ct] = __builtin_amdgcn_mfma_f32_16x16x32_bf16(ah[rz + 1], bzl[ct], accz[rz][ct], 0, 0, 0);
        accz[rz][ct] = __builtin_amdgcn_mfma_f32_16x16x32_bf16(al[rz + 1], bzh[ct], accz[rz][ct], 0, 0, 0);
      }
  }
  // zs epilogue (identical expression: v *= sigm(v); pack_hl)
#pragma unroll
  for (int rz = 0; rz < 2; rz++)
#pragma unroll
    for (int ct = 0; ct < 4; ct++)
#pragma unroll
      for (int r = 0; r < 4; r++) {
        int row = m0 + rz * 16 + quad * 4 + r;
        int col = wave * 64 + ct * 16 + r16;
        float v = accz[rz][ct][r];
        v *= sigm(v);
        zs_pk[(size_t)row * DI + col] = pack_hl(v);
      }
  // xm -> LDS packed (rows m0-3..m0+31 => lidx 0..34)
#pragma unroll
  for (int rt = 0; rt < 3; rt++)
#pragma unroll
    for (int ct = 0; ct < 4; ct++)
#pragma unroll
      for (int r = 0; r < 4; r++) {
        int lidx = rt * 16 + quad * 4 + r - 13;
        if (lidx >= 0)
          buf[lidx * 260 + wave * 64 + ct * 16 + r16] = pack_hl(accx[rt][ct][r]);
      }
  __syncthreads();

  // ---- phase B: conv + SiLU. Thread d: channel d over 32 rows. Writes the
  // packed u IN-PLACE into buf[t][d] (cell read by the same thread at step
  // t-3, or pre-loop for t<3 => per-thread read-before-write, race-free).
  {
    int d = tid;
    float4 w4 = *(const float4*)(cw + d * 4);
    float w0 = w4.x, w1 = w4.y, w2 = w4.z, w3 = w4.w;
    float bias = cb[d];
    float xa = unpack_hl(buf[0 * 260 + d]);
    float xb = unpack_hl(buf[1 * 260 + d]);
    float xc = unpack_hl(buf[2 * 260 + d]);
    int lbase = m0 & (LL - 1);
#pragma unroll 4
    for (int t = 0; t < 32; t++) {
      float xd = unpack_hl(buf[(t + 3) * 260 + d]);
      int l = lbase + t;
      float x0 = xa * ((l >= 3) ? 1.f : 0.f);
      float x1 = xb * ((l >= 2) ? 1.f : 0.f);
      float x2 = xc * ((l >= 1) ? 1.f : 0.f);
      float c0 = bias + w0 * x0 + w1 * x1 + w2 * x2 + w3 * xd;
      float u = c0 * sigm(c0);
      short hs, ls; split_bits2(u, hs, ls);
      uint up = pk2(hs, ls);
      u_pk[(size_t)(m0 + t) * DI + d] = up;
      buf[t * 260 + d] = up;
      xa = xb; xb = xc; xc = xd;
    }
  }
  __syncthreads();   // u rows 0..31 complete in buf; rows 32..34 dead -> sx

  // ---- phase C: x_proj GEMM. 6 tiles over 4 waves; A-frags unpacked from
  // LDS u (same bits as old ubh/ubl). Results -> global C; cols 0..23 also
  // -> LDS sxp (rows 32..34 region, stride 24) for phase D.
  float* sxp = (float*)(buf + 32 * 260);   // 768 floats <= 780 free
  {
    int rt0 = (wave == 3) ? 1 : 0;
    int ct0 = (wave == 0) ? 0 : (wave == 1) ? 1 : (wave == 2) ? 2 : 0;
#pragma unroll 1
    for (int tt = 0; tt < 2; tt++) {
      int rt, ct;
      if (tt == 0) { rt = rt0; ct = ct0; }
      else { if (wave >= 2) break; rt = 1; ct = wave + 1; }
      f32x4 a2 = {};
#pragma unroll
      for (int kk = 0; kk < 8; kk++) {
        int k0 = quad * 8 + kk * 32;
        const uint* ub = buf + (rt * 16 + r16) * 260 + k0;
        bf16x8 ahh, alo;
#pragma unroll
        for (int e = 0; e < 8; e++) {
          uint w = ub[e];
          ahh[e] = (short)(w & 0xffffu);
          alo[e] = (short)(w >> 16);
        }
        size_t br = (size_t)(ct * 16 + r16) * DI + quad * 8 + kk * 32;
        bf16x8 bhh = *(const bf16x8*)(Xh + br);
        bf16x8 blo = *(const bf16x8*)(Xl + br);
        a2 = __builtin_amdgcn_mfma_f32_16x16x32_bf16(ahh, bhh, a2, 0, 0, 0);
        a2 = __builtin_amdgcn_mfma_f32_16x16x32_bf16(ahh, blo, a2, 0, 0, 0);
        a2 = __builtin_amdgcn_mfma_f32_16x16x32_bf16(alo, bhh, a2, 0, 0, 0);
      }
#pragma unroll
      for (int r = 0; r < 4; r++) {
        int row = rt * 16 + quad * 4 + r;
        int col = ct * 16 + r16;
        C[(size_t)(m0 + row) * 64 + col] = a2[r];
        if (col < 24) sxp[row * 24 + col] = a2[r];
      }
    }
  }
  __syncthreads();

  // ---- phase D: scan_phase1; u + x both from LDS. Thread d = channel d.
  {
    int b = blockIdx.x >> 6, s = blockIdx.x & 63, d = tid;
    if (a_is_integer(A_log, d))
      scan1_lds2<true>(s, b, d, sxp, buf, dtw, dtb, A_log, sega, segh);
    else
      scan1_lds2<false>(s, b, d, sxp, buf, dtw, dtb, A_log, sega, segh);
  }
}

// ---------------------------------------------------------------------------
// FUSED encoder + RMSNorm (layer-0 prologue), bitwise-identical.
// ---------------------------------------------------------------------------
__global__ __launch_bounds__(256) void enc_norm_kernel(const float* __restrict__ x,
    const float* __restrict__ ew, const float* __restrict__ eb,
    const float* __restrict__ w, float* __restrict__ h,
    bf16* __restrict__ oh, bf16* __restrict__ ol) {
  int lane = threadIdx.x & 63;
  int pos = blockIdx.x * 4 + (threadIdx.x >> 6);
  const float* xr = x + (size_t)pos * 12;
  float v0 = eb[lane], v1 = eb[lane + 64];
#pragma unroll
  for (int c = 0; c < 12; c++) {
    float xv = xr[c];
    v0 += xv * ew[lane * 12 + c];
    v1 += xv * ew[(lane + 64) * 12 + c];
  }
  size_t o = (size_t)pos * DM;
  h[o + lane] = v0;
  h[o + lane + 64] = v1;
  float ss = v0 * v0 + v1 * v1;
#pragma unroll
  for (int off = 1; off < 64; off <<= 1) ss += __shfl_xor(ss, off);
  float sc = rsqrtf(ss * (1.f / DM) + 1e-5f);
  float a = v0 * sc * w[lane], b = v1 * sc * w[lane + 64];
  bf16split(a, oh[o + lane], ol[o + lane]);
  bf16split(b, oh[o + lane + 64], ol[o + lane + 64]);
}

// ---------------------------------------------------------------------------
// Weight splits
// ---------------------------------------------------------------------------
__global__ void split_w(const float* __restrict__ src, bf16* __restrict__ hi,
                        bf16* __restrict__ lo, int n) {
  int i = blockIdx.x * 256 + threadIdx.x;
  if (i < n) bf16split(src[i], hi[i], lo[i]);
}

__global__ void split_w_pad(const float* __restrict__ src, bf16* __restrict__ hi,
                            bf16* __restrict__ lo) {
  int i = blockIdx.x * 256 + threadIdx.x;   // < 4*64*256
  int l = i >> 14, rem = i & 16383, r = rem >> 8, k = rem & 255;
  float v = (r < 40) ? src[l * 10240 + r * 256 + k] : 0.f;
  bf16split(v, hi[i], lo[i]);
}

// load 32 rows x 40 cols of xdbl (cols 0..39) into LDS, stride XSTR
__device__ inline void load_sx(float* sx, const float* xdbl, size_t rbase, int tid) {
#pragma unroll
  for (int j = 0; j < 2; j++) {
    int idx = j * 256 + tid;       // < 320 = 32 rows x 10 float4
    if (idx < 320) {
      int row = idx / 10, c = idx % 10;
      *(float4*)(sx + row * XSTR + c * 4) = *(const float4*)(xdbl + rbase + row * 64 + c * 4);
    }
  }
}

// ---------------------------------------------------------------------------
// scan_combine, 65536 scalar chains over 256 blocks (every CU active).
// ---------------------------------------------------------------------------
__global__ __launch_bounds__(256) void scan_combine(float* __restrict__ sega,
    const float* __restrict__ segh) {
  int g = blockIdx.x * 256 + threadIdx.x;   // chain id = (b*256+d)*16+n
  float h0 = 0.f;
  for (int s = 0; s < NSEG; s++) {
    size_t q = (size_t)s * 65536 + g;
    float a = sega[q];
    float hh = segh[q];
    sega[q] = h0;
    h0 = a * h0 + hh;
  }
}

// ---------------------------------------------------------------------------
// scan2: FUSED scan_phase2 + out_proj + residual + RMSNorm.
// R15: exact R13 form restored. R14's YSTR=240 shave was a BUG: rows hold
// d in [0,256) so YSTR must be >= 256 — 240 overlapped adjacent rows by 16
// shorts (absmax 0 -> 2.4e-4). The 20,480 B (8 blocks/CU) target is
// arithmetically impossible with a legal stride; lever retired.
// ---------------------------------------------------------------------------
template<bool FAST>
__device__ inline void scan2_to_lds(int s, int b, int d, const float* sx,
    const uint* __restrict__ u_pk, const uint* __restrict__ zs_pk,
    const float* __restrict__ dtw, const float* __restrict__ dtb,
    const float* __restrict__ A_log, const float* __restrict__ Dp,
    const float* __restrict__ sega, short* __restrict__ ybuf) {
  float wdt[8];
#pragma unroll
  for (int j = 0; j < 8; j++) wdt[j] = dtw[d * 8 + j];
  float bdt = dtb[d];
  float h[DS];
  size_t o = ((size_t)s * 4096 + b * 256 + d) * DS;
#pragma unroll
  for (int n = 0; n < DS; n++) h[n] = sega[o + n];
  float Dd = Dp[d];
  size_t base = (size_t)b * LL + (size_t)s * SEGLEN;
  const uint* up = u_pk + base * DI + d;
  const uint* zp = zs_pk + base * DI + d;
  uint ub = *up, zb = *zp;
#pragma unroll 4
  for (int t = 0; t < SEGLEN; t++) {
    up += DI; zp += DI;
    uint ub_next = *up;
    uint zb_next = *zp;
    const float* xr = sx + t * XSTR;
    float dt = bdt;
#pragma unroll
    for (int j = 0; j < 8; j++) dt += xr[j] * wdt[j];
    float dl = softplus_f(dt);
    float u = unpack_hl(ub);
    float du = dl * u;
    float acc = 0.f;
    if (FAST) {
      float rp[DS];
      make_powers(__expf(-dl), rp);
#pragma unroll
      for (int n = 0; n < DS; n++) {
        h[n] = fmaf(rp[n], h[n], du * xr[8 + n]);
        acc = fmaf(h[n], xr[24 + n], acc);
      }
    } else {
#pragma unroll
      for (int n = 0; n < DS; n++) {
        float dA = __expf(dl * (-__expf(A_log[d * DS + n])));
        h[n] = fmaf(dA, h[n], du * xr[8 + n]);
        acc = fmaf(h[n], xr[24 + n], acc);
      }
    }
    float zs = unpack_hl(zb);
    float yv = (acc + u * Dd) * zs;
    ybuf[t * YSTR + d] = bfbits(yv);
    ub = ub_next; zb = zb_next;
  }
}

__global__ __launch_bounds__(256, 7) void scan2_outproj(
    const uint* __restrict__ u_pk, const uint* __restrict__ zs_pk,
    const float* __restrict__ xdbl, const float* __restrict__ dtw,
    const float* __restrict__ dtb, const float* __restrict__ A_log,
    const float* __restrict__ Dp, const float* __restrict__ sega,
    const bf16* __restrict__ Wh, const bf16* __restrict__ Wl,
    float* __restrict__ hbuf, const float* __restrict__ nw,
    float* __restrict__ of, bf16* __restrict__ oh, bf16* __restrict__ ol) {
  __shared__ float sx[SEGLEN * XSTR];      // 5 KB
  __shared__ short ybuf[32 * YSTR];        // 16.9 KB (bf16 y; later fp32 tile)
  int s = blockIdx.x, b = blockIdx.y;
  int tid = threadIdx.x, d = tid;
  size_t rbase = ((size_t)b * LL + (size_t)s * SEGLEN) * 64;
  load_sx(sx, xdbl, rbase, tid);
  __syncthreads();
  if (a_is_integer(A_log, d))
    scan2_to_lds<true>(s, b, d, sx, u_pk, zs_pk, dtw, dtb, A_log, Dp, sega, ybuf);
  else
    scan2_to_lds<false>(s, b, d, sx, u_pk, zs_pk, dtw, dtb, A_log, Dp, sega, ybuf);
  __syncthreads();
  // out_proj: C[32x128] = y[32x256] @ Wop[128x256]^T, wave covers 32 cols
  int wave = tid >> 6, lane = tid & 63;
  int r16 = lane & 15, quad = lane >> 4;
  int n0 = wave * 32;
  size_t brow[2];
#pragma unroll
  for (int j = 0; j < 2; j++)
    brow[j] = (size_t)(n0 + j * 16 + r16) * DI + quad * 8;
  f32x4 acc[2][2] = {};
#pragma unroll
  for (int kk = 0; kk < 8; kk++) {
    int k0 = quad * 8 + kk * 32;
    bf16x8 ah[2], bh[2], bl[2];
#pragma unroll
    for (int i = 0; i < 2; i++)
      ah[i] = *(const bf16x8*)(ybuf + (i * 16 + r16) * YSTR + k0);
#pragma unroll
    for (int j = 0; j < 2; j++) {
      bh[j] = *(const bf16x8*)(Wh + brow[j] + kk * 32);
      bl[j] = *(const bf16x8*)(Wl + brow[j] + kk * 32);
    }
#pragma unroll
    for (int i = 0; i < 2; i++)
#pragma unroll
      for (int j = 0; j < 2; j++) {
        acc[i][j] = __builtin_amdgcn_mfma_f32_16x16x32_bf16(ah[i], bh[j], acc[i][j], 0, 0, 0);
        acc[i][j] = __builtin_amdgcn_mfma_f32_16x16x32_bf16(ah[i], bl[j], acc[i][j], 0, 0, 0);
      }
  }
  __syncthreads();   // all LDS y reads done; reuse ybuf as fp32 tile 32x132
  float* tile = (float*)ybuf;
#pragma unroll
  for (int i = 0; i < 2; i++)
#pragma unroll
    for (int j = 0; j < 2; j++)
#pragma unroll
      for (int r = 0; r < 4; r++) {
        int rl = i * 16 + quad * 4 + r;
        int col = n0 + j * 16 + r16;
        tile[rl * 132 + col] = acc[i][j][r];
      }
  __syncthreads();
  // epilogue: residual + rmsnorm + bf16 split, coalesced
  size_t mbase = (size_t)b * LL + (size_t)s * SEGLEN;
#pragma unroll
  for (int it = 0; it < 4; it++) {
    int idx = it * 256 + tid;
    int row = idx >> 5, c4 = idx & 31;
    size_t g = (mbase + row) * DM + c4 * 4;
    float4 hv = *(float4*)(hbuf + g);
    const float* tp = tile + row * 132 + c4 * 4;
    float4 v = make_float4(tp[0] + hv.x, tp[1] + hv.y, tp[2] + hv.z, tp[3] + hv.w);
    *(float4*)(hbuf + g) = v;
    float ss = v.x * v.x + v.y * v.y + v.z * v.z + v.w * v.w;
    ss += __shfl_xor(ss, 1);
    ss += __shfl_xor(ss, 2);
    ss += __shfl_xor(ss, 4);
    ss += __shfl_xor(ss, 8);
    ss += __shfl_xor(ss, 16);
    float sc = rsqrtf(ss * (1.f / DM) + 1e-5f);
    float4 w4 = *(const float4*)(nw + c4 * 4);
    float n0v = v.x * sc * w4.x, n1v = v.y * sc * w4.y;
    float n2v = v.z * sc * w4.z, n3v = v.w * sc * w4.w;
    if (of) *(float4*)(of + g) = make_float4(n0v, n1v, n2v, n3v);
    short h0s, l0s, h1s, l1s, h2s, l2s, h3s, l3s;
    split_bits2(n0v, h0s, l0s); split_bits2(n1v, h1s, l1s);
    split_bits2(n2v, h2s, l2s); split_bits2(n3v, h3s, l3s);
    bf16x4s hb, lb;
    hb[0] = h0s; hb[1] = h1s; hb[2] = h2s; hb[3] = h3s;
    lb[0] = l0s; lb[1] = l1s; lb[2] = l2s; lb[3] = l3s;
    *(bf16x4s*)(oh + g) = hb;
    *(bf16x4s*)(ol + g) = lb;
  }
}

// ---------------------------------------------------------------------------
// Pooling (deterministic) + classifier
// ---------------------------------------------------------------------------
__global__ __launch_bounds__(256) void pool_partial(const float* __restrict__ fn,
    float* __restrict__ partial) {
  __shared__ float red[256];
  int b = blockIdx.x, c = blockIdx.y;
  int tid = threadIdx.x;
  int d = tid & 127, rp_ = tid >> 7;
  float s = 0.f;
  size_t base = (size_t)b * LL + c * 256;
  for (int i = 0; i < 128; i++) {
    int row = i * 2 + rp_;
    s += fn[(base + row) * DM + d];
  }
  red[tid] = s;
  __syncthreads();
  if (tid < 128) partial[((size_t)b * 8 + c) * 128 + tid] = red[tid] + red[tid + 128];
}

__global__ void pool_reduce(const float* __restrict__ partial,
    float* __restrict__ pooled) {
  int idx = blockIdx.x * 256 + threadIdx.x;   // 2048
  int b = idx >> 7, d = idx & 127;
  float s = 0.f;
#pragma unroll
  for (int c = 0; c < 8; c++) s += partial[((size_t)b * 8 + c) * 128 + d];
  pooled[idx] = s * (1.f / LL);
}

__global__ void cls_kernel(const float* __restrict__ pooled,
    const float* __restrict__ cw, const float* __restrict__ cb,
    float* __restrict__ out) {
  int t = threadIdx.x;
  if (t < 80) {
    int b = t / 5, c = t % 5;
    float acc = cb[c];
    for (int d = 0; d < DM; d++) acc += pooled[b * DM + d] * cw[c * DM + d];
    out[t] = acc;
  }
}

// ---------------------------------------------------------------------------
extern "C" void kernel_launch(void* const* d_in, const int* in_sizes, int n_in,
                              void* d_out, int out_size, void* d_ws, size_t ws_size,
                              hipStream_t stream) {
  const float* x         = (const float*)d_in[0];
  const float* enc_w     = (const float*)d_in[1];
  const float* enc_b     = (const float*)d_in[2];
  const float* norm_w    = (const float*)d_in[3];
  const float* in_proj_w = (const float*)d_in[4];
  const float* conv_w    = (const float*)d_in[5];
  const float* conv_b    = (const float*)d_in[6];
  const float* x_proj_w  = (const float*)d_in[7];
  const float* dt_proj_w = (const float*)d_in[8];
  const float* dt_proj_b = (const float*)d_in[9];
  const float* A_log     = (const float*)d_in[10];
  const float* Dp        = (const float*)d_in[11];
  const float* out_proj_w= (const float*)d_in[12];
  const float* norm_f_w  = (const float*)d_in[13];
  const float* cls_w     = (const float*)d_in[14];
  const float* cls_b     = (const float*)d_in[15];
  float* out = (float*)d_out;

  float* ws = (float*)d_ws;
  float* h       = ws;                       // 4,194,304
  float* xdbl    = ws + 4194304;             // 2,097,152
  float* sega    = ws + 6291456;             // 4,194,304
  float* segh    = ws + 10485760;            // 4,194,304
  uint*  zs_pk   = (uint*)(ws + 14680064);   // 8,388,608
  uint*  u_pk    = (uint*)(ws + 23068672);   // 8,388,608
  uint*  xm_pk   = (uint*)(ws + 31457280);   // fnorm alias
  float* partial = ws + 39845888;            // 16,384
  float* pooled  = ws + 39862272;            // 2,048
  bf16* u0     = (bf16*)(ws + 39864320);
  bf16* xn_hi  = u0;                         // MP*128
  bf16* xn_lo  = u0 + 4194304;
  bf16* wip_hi = u0 + 8388608;               // 262,144
  bf16* wip_lo = wip_hi + 262144;
  bf16* wxp_hi = wip_lo + 262144;            // 65,536 (padded)
  bf16* wxp_lo = wxp_hi + 65536;
  bf16* wop_hi = wxp_lo + 65536;             // 131,072
  bf16* wop_lo = wop_hi + 131072;
  float* fnorm = (float*)xm_pk;

  split_w<<<1024, 256, 0, stream>>>(in_proj_w, wip_hi, wip_lo, 262144);
  split_w_pad<<<256, 256, 0, stream>>>(x_proj_w, wxp_hi, wxp_lo);
  split_w<<<512, 256, 0, stream>>>(out_proj_w, wop_hi, wop_lo, 131072);

  enc_norm_kernel<<<MP / 4, 256, 0, stream>>>(x, enc_w, enc_b, norm_w, h,
                                              xn_hi, xn_lo);

  for (int i = 0; i < 4; i++) {
    gemm_inproj_conv<<<MP / 32, 256, 0, stream>>>(xn_hi, xn_lo,
        wip_hi + i * 65536, wip_lo + i * 65536,
        wxp_hi + i * 16384, wxp_lo + i * 16384,
        conv_w + i * DI * 4, conv_b + i * DI,
        dt_proj_w + i * 2048, dt_proj_b + i * DI, A_log + i * DI * DS,
        zs_pk, u_pk, xdbl, sega, segh);
    scan_combine<<<256, 256, 0, stream>>>(sega, segh);
    scan2_outproj<<<dim3(NSEG, BB), 256, 0, stream>>>(u_pk, zs_pk, xdbl,
        dt_proj_w + i * 2048, dt_proj_b + i * DI, A_log + i * DI * DS,
        Dp + i * DI, sega, wop_hi + i * 32768, wop_lo + i * 32768, h,
        (i < 3) ? norm_w + (i + 1) * DM : norm_f_w,
        (i < 3) ? nullptr : fnorm, xn_hi, xn_lo);
  }

  pool_partial<<<dim3(BB, 8), 256, 0, stream>>>(fnorm, partial);
  pool_reduce<<<8, 256, 0, stream>>>(partial, pooled);
  cls_kernel<<<1, 128, 0, stream>>>(pooled, cls_w, cls_b, out);
}